// Round 7
// baseline (1391.699 us; speedup 1.0000x reference)
//
#include <hip/hip_runtime.h>
#include <cmath>

// Problem constants
#define NB 8
#define NPTS 4096
#define NPT 1024
#define NSAMP 32
#define MTOT (NB*NPT*NSAMP)   // 262144 rows for the MLP
#define NBLK 4096             // MTOT/64 GEMM blocks

typedef float v2f __attribute__((ext_vector_type(2)));

// ---------------------------------------------------------------------------
// Stage 1: farthest point sampling. One block of 8 waves per batch.
// Bitwise-exact f32 replication of the reference (packed mul/add with
// contraction OFF; (dx2+dy2)+dz2 order; argmax first-index tie-break).
// Critical-path structure (only ONE LDS write + barrier + pipelined reads):
//   dist -> pk value tree -> 32-bit DPP wave max -> readlane ->
//   8x ballot vs wave max -> SALU first-nonzero scan -> (ord,wlane) ->
//   winner lane selects its candidate coords from ITS OWN registers and
//   writes key+coords to the wave slot -> barrier -> 10 independent
//   broadcast b128 reads (keys+coords SoA) -> key sel tree + depth-3
//   cndmask coord select. No sxyz table, no dependent far-lookup.
// ---------------------------------------------------------------------------
__global__ __launch_bounds__(512) void fps_kernel(const float* __restrict__ xyz,
                                                  float* __restrict__ new_xyz) {
#pragma clang fp contract(off)
  const int b = blockIdx.x;
  const int t = threadIdx.x;          // 0..511
  const int wv = t >> 6;              // 0..7
  const int lane = t & 63;
  __shared__ float4 sout[NPT];                       // 16 KiB centroid history
  __shared__ __align__(16) unsigned long long skey[2][8];
  __shared__ __align__(16) float scoord[2][3][8];    // [par][coord][wave]
  const float* X = xyz + (size_t)b * NPTS * 3;
  v2f px[4], py[4], pz[4], dist[4];
#pragma unroll
  for (int i = 0; i < 4; ++i) {
    int p0 = (2 * i) * 512 + t;
    int p1 = (2 * i + 1) * 512 + t;
    float x0 = X[p0 * 3 + 0], y0 = X[p0 * 3 + 1], z0 = X[p0 * 3 + 2];
    float x1 = X[p1 * 3 + 0], y1 = X[p1 * 3 + 1], z1 = X[p1 * 3 + 2];
    px[i] = (v2f){x0, x1}; py[i] = (v2f){y0, y1}; pz[i] = (v2f){z0, z1};
    dist[i] = (v2f){1e10f, 1e10f};
  }
  float ccx = X[0], ccy = X[1], ccz = X[2];          // first centroid = point 0
  for (int s = 0; s < NPT; ++s) {
    if (t == 0) sout[s] = make_float4(ccx, ccy, ccz, 0.0f);
    v2f cx = (v2f){ccx, ccx}, cy = (v2f){ccy, ccy}, cz = (v2f){ccz, ccz};
    v2f nd[4];
#pragma unroll
    for (int i = 0; i < 4; ++i) {
      v2f dx = px[i] - cx;
      v2f dy = py[i] - cy;
      v2f dz = pz[i] - cz;
      v2f d = (dx * dx + dy * dy) + dz * dz;         // contract(off): ref order
      v2f m = __builtin_elementwise_min(dist[i], d);
      dist[i] = m;
      nd[i] = m;
    }
    // per-lane max value: depth-2 pk tree + halves merge
    v2f t01 = __builtin_elementwise_max(nd[0], nd[1]);
    v2f t23 = __builtin_elementwise_max(nd[2], nd[3]);
    v2f t03 = __builtin_elementwise_max(t01, t23);
    float lmax = fmaxf(t03.x, t03.y);
    // 32-bit DPP wave max on value bits (all values >= +0 -> unsigned order)
    unsigned km = __float_as_uint(lmax);
    {
      unsigned o;
      o = (unsigned)__builtin_amdgcn_update_dpp(0, (int)km, 0x111, 0xf, 0xf, false);
      km = o > km ? o : km;   // row_shr:1
      o = (unsigned)__builtin_amdgcn_update_dpp(0, (int)km, 0x112, 0xf, 0xf, false);
      km = o > km ? o : km;   // row_shr:2
      o = (unsigned)__builtin_amdgcn_update_dpp(0, (int)km, 0x114, 0xf, 0xf, false);
      km = o > km ? o : km;   // row_shr:4
      o = (unsigned)__builtin_amdgcn_update_dpp(0, (int)km, 0x118, 0xf, 0xf, false);
      km = o > km ? o : km;   // row_shr:8
      o = (unsigned)__builtin_amdgcn_update_dpp(0, (int)km, 0x142, 0xf, 0xf, false);
      km = o > km ? o : km;   // row_bcast:15
      o = (unsigned)__builtin_amdgcn_update_dpp(0, (int)km, 0x143, 0xf, 0xf, false);
      km = o > km ? o : km;   // row_bcast:31
    }
    unsigned wmax = (unsigned)__builtin_amdgcn_readlane((int)km, 63);  // uniform
    // ballots per ordinal (ordinal k = point k*512 + t); independent v_cmps
    unsigned long long m0 = __ballot(__float_as_uint(nd[0].x) == wmax);
    unsigned long long m1 = __ballot(__float_as_uint(nd[0].y) == wmax);
    unsigned long long m2 = __ballot(__float_as_uint(nd[1].x) == wmax);
    unsigned long long m3 = __ballot(__float_as_uint(nd[1].y) == wmax);
    unsigned long long m4 = __ballot(__float_as_uint(nd[2].x) == wmax);
    unsigned long long m5 = __ballot(__float_as_uint(nd[2].y) == wmax);
    unsigned long long m6 = __ballot(__float_as_uint(nd[3].x) == wmax);
    unsigned long long m7 = __ballot(__float_as_uint(nd[3].y) == wmax);
    // first-nonzero scan, prefer smallest ordinal (uniform -> SALU)
    unsigned long long mk = m7; int ord = 7;
    if (m6) { mk = m6; ord = 6; }
    if (m5) { mk = m5; ord = 5; }
    if (m4) { mk = m4; ord = 4; }
    if (m3) { mk = m3; ord = 3; }
    if (m2) { mk = m2; ord = 2; }
    if (m1) { mk = m1; ord = 1; }
    if (m0) { mk = m0; ord = 0; }
    int wlane = (int)__builtin_ctzll(mk);            // smallest lane in wave
    int idx = ord * 512 + wv * 64 + wlane;           // global point index
    // key: higher value wins; equal value -> smaller index wins
    unsigned long long key = ((unsigned long long)wmax << 32)
                           | (unsigned int)(~idx);
    // candidate coord select by uniform ord (every lane computes; only the
    // winner lane's values are used). reg = ord>>1, half = ord&1.
    int ih = ord >> 1;
    bool hf = ord & 1;
    v2f xa = (ih & 1) ? px[1] : px[0];
    v2f xb = (ih & 1) ? px[3] : px[2];
    v2f xs = (ih & 2) ? xb : xa;
    float kx = hf ? xs.y : xs.x;
    v2f ya = (ih & 1) ? py[1] : py[0];
    v2f yb = (ih & 1) ? py[3] : py[2];
    v2f ys = (ih & 2) ? yb : ya;
    float ky = hf ? ys.y : ys.x;
    v2f za = (ih & 1) ? pz[1] : pz[0];
    v2f zb = (ih & 1) ? pz[3] : pz[2];
    v2f zs = (ih & 2) ? zb : za;
    float kz = hf ? zs.y : zs.x;
    int par = s & 1;
    if (lane == wlane) {                              // unique lane per wave
      skey[par][wv] = key;
      scoord[par][0][wv] = kx;
      scoord[par][1][wv] = ky;
      scoord[par][2][wv] = kz;
    }
    __syncthreads();
    // pipelined independent broadcast reads: 4 (keys) + 6 (coords) x b128
    const ulonglong2* sk = (const ulonglong2*)skey[par];
    ulonglong2 A = sk[0], B = sk[1], C = sk[2], D = sk[3];
    float4 cx0 = *(const float4*)&scoord[par][0][0];
    float4 cx1 = *(const float4*)&scoord[par][0][4];
    float4 cy0 = *(const float4*)&scoord[par][1][0];
    float4 cy1 = *(const float4*)&scoord[par][1][4];
    float4 cz0 = *(const float4*)&scoord[par][2][0];
    float4 cz1 = *(const float4*)&scoord[par][2][4];
    // key max tree
    unsigned long long a = A.x > A.y ? A.x : A.y;
    unsigned long long bq = B.x > B.y ? B.x : B.y;
    unsigned long long c = C.x > C.y ? C.x : C.y;
    unsigned long long dq = D.x > D.y ? D.x : D.y;
    unsigned long long ab = a > bq ? a : bq;
    unsigned long long cd = c > dq ? c : dq;
    unsigned long long kf = ab > cd ? ab : cd;
    int far = (int)(~(unsigned int)kf) & (NPTS - 1);
    int ww = (far >> 6) & 7;                          // winning wave slot
    // depth-3 cndmask select of the winning slot's coords
    float x0s = (ww & 1) ? cx0.y : cx0.x;
    float x1s = (ww & 1) ? cx0.w : cx0.z;
    float x2s = (ww & 1) ? cx1.y : cx1.x;
    float x3s = (ww & 1) ? cx1.w : cx1.z;
    float xm0 = (ww & 2) ? x1s : x0s;
    float xm1 = (ww & 2) ? x3s : x2s;
    ccx = (ww & 4) ? xm1 : xm0;
    float y0s = (ww & 1) ? cy0.y : cy0.x;
    float y1s = (ww & 1) ? cy0.w : cy0.z;
    float y2s = (ww & 1) ? cy1.y : cy1.x;
    float y3s = (ww & 1) ? cy1.w : cy1.z;
    float ym0 = (ww & 2) ? y1s : y0s;
    float ym1 = (ww & 2) ? y3s : y2s;
    ccy = (ww & 4) ? ym1 : ym0;
    float z0s = (ww & 1) ? cz0.y : cz0.x;
    float z1s = (ww & 1) ? cz0.w : cz0.z;
    float z2s = (ww & 1) ? cz1.y : cz1.x;
    float z3s = (ww & 1) ? cz1.w : cz1.z;
    float zm0 = (ww & 2) ? z1s : z0s;
    float zm1 = (ww & 2) ? z3s : z2s;
    ccz = (ww & 4) ? zm1 : zm0;
  }
  __syncthreads();
  float* outp = new_xyz + (size_t)b * NPT * 3;
  for (int j = t; j < NPT; j += 512) {
    float4 cc = sout[j];
    outp[3 * j + 0] = cc.x; outp[3 * j + 1] = cc.y; outp[3 * j + 2] = cc.z;
  }
}

// ---------------------------------------------------------------------------
// Stage 2: ball query. One wave per (b,s). First 32 indices in ascending order
// with dist <= r^2; pad with first match.
// ---------------------------------------------------------------------------
__global__ __launch_bounds__(256) void ballq_kernel(const float* __restrict__ xyz,
                                                    const float* __restrict__ new_xyz,
                                                    int* __restrict__ gidx) {
  int w = (blockIdx.x * 256 + threadIdx.x) >> 6;   // 8192 waves
  int lane = threadIdx.x & 63;
  int b = w >> 10;
  const float* X = xyz + (size_t)b * NPTS * 3;
  float cx = new_xyz[w * 3 + 0], cy = new_xyz[w * 3 + 1], cz = new_xyz[w * 3 + 2];
  int* out = gidx + (size_t)w * NSAMP;
  int cnt = 0, first = -1;
  for (int c = 0; c < NPTS / 64; ++c) {
    int p = c * 64 + lane;
    float dx = __fsub_rn(X[p * 3 + 0], cx);
    float dy = __fsub_rn(X[p * 3 + 1], cy);
    float dz = __fsub_rn(X[p * 3 + 2], cz);
    float d = __fadd_rn(__fadd_rn(__fmul_rn(dx, dx), __fmul_rn(dy, dy)), __fmul_rn(dz, dz));
    bool inr = !(d > 0.04f);   // f32(0.2**2) == 0.04f
    unsigned long long mask = __ballot(inr);
    if (mask) {
      if (first < 0) first = c * 64 + (int)__builtin_ctzll(mask);
      if (inr) {
        int pos = cnt + (int)__builtin_popcountll(mask & ((1ull << lane) - 1ull));
        if (pos < NSAMP) out[pos] = p;
      }
      cnt += (int)__builtin_popcountll(mask);
      if (cnt >= NSAMP) break;
    }
  }
  if (lane >= cnt && lane < NSAMP) out[lane] = first;
}

// ---------------------------------------------------------------------------
// Stage 4a: layer-1 GEMM with FUSED gather (no X0 materialization).
// Column layout permuted to [pts(64) | dxyz(3) | pad]; weights permuted to
// match while staging. 64x64 tile per block, 256 threads.
// ---------------------------------------------------------------------------
__global__ __launch_bounds__(256) void mlp_gemm_gather(
    const float* __restrict__ xyz, const float* __restrict__ points,
    const float* __restrict__ new_xyz, const int* __restrict__ gidx,
    const float* __restrict__ Wg, const float* __restrict__ bias,
    float* __restrict__ Yg, float* __restrict__ partials) {
  constexpr int O = 64, OJ = 4, KP4 = 17;
  __shared__ __align__(16) float sX[64 * 68];
  __shared__ __align__(16) float sWt[68 * O];
  const int t = threadIdx.x;
  const int m0 = blockIdx.x * 64;

  // stage W with permuted rows: k<64 -> W[o*67+k+3]; 64..66 -> W[o*67+k-64]; 67 -> 0
  for (int i = t; i < O * 68; i += 256) {
    int k = i >> 6, o = i & 63;
    float w;
    if (k < 64) w = Wg[o * 67 + k + 3];
    else if (k < 67) w = Wg[o * 67 + (k - 64)];
    else w = 0.0f;
    sWt[k * O + o] = w;
  }
  // stage X tile directly from gathered points/xyz
  {
    int r = t >> 2, q = t & 3;
    int m = m0 + r;
    int idx = gidx[m];
    int b = m >> 15;
    const float* prow = points + ((size_t)b * NPTS + idx) * 64;
#pragma unroll
    for (int c4 = q; c4 < 16; c4 += 4)
      *(float4*)&sX[r * 68 + 4 * c4] = *(const float4*)(prow + 4 * c4);
    if (q == 0) {
      int g = m >> 5;
      const float* xr = xyz + ((size_t)b * NPTS + idx) * 3;
      sX[r * 68 + 64] = __fsub_rn(xr[0], new_xyz[g * 3 + 0]);
      sX[r * 68 + 65] = __fsub_rn(xr[1], new_xyz[g * 3 + 1]);
      sX[r * 68 + 66] = __fsub_rn(xr[2], new_xyz[g * 3 + 2]);
      sX[r * 68 + 67] = 0.0f;
    }
  }
  __syncthreads();

  const int to = t & 15, tm = t >> 4;
  float acc[4][OJ];
#pragma unroll
  for (int i = 0; i < 4; ++i)
#pragma unroll
    for (int j = 0; j < OJ; ++j) acc[i][j] = 0.0f;

#pragma unroll
  for (int k4 = 0; k4 < KP4; ++k4) {
    float xs[4][4];
#pragma unroll
    for (int i = 0; i < 4; ++i) {
      float4 v = *(const float4*)&sX[(4 * tm + i) * 68 + 4 * k4];
      xs[i][0] = v.x; xs[i][1] = v.y; xs[i][2] = v.z; xs[i][3] = v.w;
    }
#pragma unroll
    for (int kk = 0; kk < 4; ++kk) {
      float4 wq = *(const float4*)&sWt[(4 * k4 + kk) * O + OJ * to];
      float wv[4] = {wq.x, wq.y, wq.z, wq.w};
#pragma unroll
      for (int i = 0; i < 4; ++i) {
        float xv = xs[i][kk];
#pragma unroll
        for (int j = 0; j < OJ; ++j) acc[i][j] = fmaf(xv, wv[j], acc[i][j]);
      }
    }
  }
#pragma unroll
  for (int j = 0; j < OJ; ++j) {
    float bb = bias[OJ * to + j];
#pragma unroll
    for (int i = 0; i < 4; ++i) acc[i][j] += bb;
  }
  float ps[OJ], ss[OJ];
#pragma unroll
  for (int j = 0; j < OJ; ++j) {
    ps[j] = ((acc[0][j] + acc[1][j]) + (acc[2][j] + acc[3][j]));
    ss[j] = ((acc[0][j] * acc[0][j] + acc[1][j] * acc[1][j]) +
             (acc[2][j] * acc[2][j] + acc[3][j] * acc[3][j]));
  }
  __syncthreads();
#pragma unroll
  for (int j = 0; j < OJ; ++j) {
    int o = OJ * to + j;
    sX[tm * O + o] = ps[j];
    sX[16 * O + tm * O + o] = ss[j];
  }
  __syncthreads();
  if (t < O) {
    float s1 = 0.0f, s2 = 0.0f;
#pragma unroll
    for (int r2 = 0; r2 < 16; ++r2) { s1 += sX[r2 * O + t]; s2 += sX[16 * O + r2 * O + t]; }
    partials[(size_t)t * NBLK + blockIdx.x] = s1;
    partials[(size_t)(O + t) * NBLK + blockIdx.x] = s2;
  }
#pragma unroll
  for (int i = 0; i < 4; ++i)
    *(float4*)&Yg[(size_t)(m0 + 4 * tm + i) * O + OJ * to] =
        make_float4(acc[i][0], acc[i][1], acc[i][2], acc[i][3]);
}

// ---------------------------------------------------------------------------
// Stage 4b: MLP layer GEMM (layers 2,3). 64xO tile per block, 256 threads.
// Applies previous layer's BN+ReLU (a,d) while staging input.
// DO_MM: max/min-pool pre-activations over k (32 rows) instead of writing Y.
// ---------------------------------------------------------------------------
template<int O, bool WRITE_Y, bool DO_MM>
__global__ __launch_bounds__(256) void mlp_gemm(const float* __restrict__ Xg,
                                                const float* __restrict__ Wg,
                                                const float* __restrict__ bias,
                                                const float* __restrict__ ad,
                                                float* __restrict__ Yg,
                                                float* __restrict__ partials,
                                                float* __restrict__ mm) {
  constexpr int KDIM = 64, KP4 = 16;
  constexpr int OJ = O / 16;            // 4 or 8
  __shared__ __align__(16) float sX[64 * 68];
  __shared__ __align__(16) float sWt[KDIM * O];
  const int t = threadIdx.x;
  const int m0 = blockIdx.x * 64;

  for (int i = t; i < O * KDIM; i += 256) {
    int k = i / O;
    int o = i - k * O;
    sWt[k * O + o] = Wg[o * KDIM + k];
  }
  {
    int r = t >> 2, q = t & 3;
    const float* src = Xg + (size_t)(m0 + r) * KDIM;
    for (int c4 = q; c4 < KP4; c4 += 4) {
      float4 v = *(const float4*)(src + 4 * c4);
      float4 a = *(const float4*)(ad + 4 * c4);
      float4 d = *(const float4*)(ad + 128 + 4 * c4);
      v.x = fmaxf(fmaf(a.x, v.x, d.x), 0.0f);
      v.y = fmaxf(fmaf(a.y, v.y, d.y), 0.0f);
      v.z = fmaxf(fmaf(a.z, v.z, d.z), 0.0f);
      v.w = fmaxf(fmaf(a.w, v.w, d.w), 0.0f);
      *(float4*)&sX[r * 68 + 4 * c4] = v;
    }
  }
  __syncthreads();

  const int to = t & 15, tm = t >> 4;
  float acc[4][OJ];
#pragma unroll
  for (int i = 0; i < 4; ++i)
#pragma unroll
    for (int j = 0; j < OJ; ++j) acc[i][j] = 0.0f;

#pragma unroll
  for (int k4 = 0; k4 < KP4; ++k4) {
    float xs[4][4];
#pragma unroll
    for (int i = 0; i < 4; ++i) {
      float4 v = *(const float4*)&sX[(4 * tm + i) * 68 + 4 * k4];
      xs[i][0] = v.x; xs[i][1] = v.y; xs[i][2] = v.z; xs[i][3] = v.w;
    }
#pragma unroll
    for (int kk = 0; kk < 4; ++kk) {
      float wv[OJ];
#pragma unroll
      for (int j4 = 0; j4 < OJ / 4; ++j4) {
        float4 wq = *(const float4*)&sWt[(4 * k4 + kk) * O + OJ * to + 4 * j4];
        wv[4 * j4 + 0] = wq.x; wv[4 * j4 + 1] = wq.y;
        wv[4 * j4 + 2] = wq.z; wv[4 * j4 + 3] = wq.w;
      }
#pragma unroll
      for (int i = 0; i < 4; ++i) {
        float xv = xs[i][kk];
#pragma unroll
        for (int j = 0; j < OJ; ++j) acc[i][j] = fmaf(xv, wv[j], acc[i][j]);
      }
    }
  }
#pragma unroll
  for (int j = 0; j < OJ; ++j) {
    float bb = bias[OJ * to + j];
#pragma unroll
    for (int i = 0; i < 4; ++i) acc[i][j] += bb;
  }
  float ps[OJ], ss[OJ];
#pragma unroll
  for (int j = 0; j < OJ; ++j) {
    ps[j] = ((acc[0][j] + acc[1][j]) + (acc[2][j] + acc[3][j]));
    ss[j] = ((acc[0][j] * acc[0][j] + acc[1][j] * acc[1][j]) +
             (acc[2][j] * acc[2][j] + acc[3][j] * acc[3][j]));
  }
  __syncthreads();
#pragma unroll
  for (int j = 0; j < OJ; ++j) {
    int o = OJ * to + j;
    sX[tm * O + o] = ps[j];
    sX[16 * O + tm * O + o] = ss[j];
  }
  __syncthreads();
  if (t < O) {
    float s1 = 0.0f, s2 = 0.0f;
#pragma unroll
    for (int r2 = 0; r2 < 16; ++r2) { s1 += sX[r2 * O + t]; s2 += sX[16 * O + r2 * O + t]; }
    partials[(size_t)t * NBLK + blockIdx.x] = s1;
    partials[(size_t)(O + t) * NBLK + blockIdx.x] = s2;
  }
  if constexpr (WRITE_Y) {
#pragma unroll
    for (int i = 0; i < 4; ++i) {
#pragma unroll
      for (int j4 = 0; j4 < OJ / 4; ++j4) {
        *(float4*)&Yg[(size_t)(m0 + 4 * tm + i) * O + OJ * to + 4 * j4] =
            make_float4(acc[i][4 * j4 + 0], acc[i][4 * j4 + 1],
                        acc[i][4 * j4 + 2], acc[i][4 * j4 + 3]);
      }
    }
  }
  if constexpr (DO_MM) {
    float vmx[OJ], vmn[OJ];
#pragma unroll
    for (int j = 0; j < OJ; ++j) {
      vmx[j] = fmaxf(fmaxf(acc[0][j], acc[1][j]), fmaxf(acc[2][j], acc[3][j]));
      vmn[j] = fminf(fminf(acc[0][j], acc[1][j]), fminf(acc[2][j], acc[3][j]));
    }
    __syncthreads();
#pragma unroll
    for (int j = 0; j < OJ; ++j) {
      int o = OJ * to + j;
      sX[tm * O + o] = vmx[j];
      sX[16 * O + tm * O + o] = vmn[j];
    }
    __syncthreads();
    int g = t >> 7, o = t & 127;
    float mx = sX[(g * 8) * O + o];
    float mn = sX[16 * O + (g * 8) * O + o];
#pragma unroll
    for (int r2 = 1; r2 < 8; ++r2) {
      mx = fmaxf(mx, sX[(g * 8 + r2) * O + o]);
      mn = fminf(mn, sX[16 * O + (g * 8 + r2) * O + o]);
    }
    int row = (m0 >> 5) + g;
    mm[(size_t)row * O + o] = mx;
    mm[(size_t)8192 * O + (size_t)row * O + o] = mn;
  }
}

// ---------------------------------------------------------------------------
// BN finalize: reduce 4096 partials per channel -> (a, d), a=g*rsigma,
// d = bt - mu*a. ad layout: a at [0..O), d at [128..128+O).
// ---------------------------------------------------------------------------
__global__ __launch_bounds__(256) void bn_finalize(const float* __restrict__ partials,
                                                   const float* __restrict__ g,
                                                   const float* __restrict__ bt,
                                                   float* __restrict__ ad, int O) {
  int o = blockIdx.x, t = threadIdx.x;
  const float* p1 = partials + (size_t)o * NBLK;
  const float* p2 = partials + (size_t)(O + o) * NBLK;
  float s1 = 0.0f, s2 = 0.0f;
  for (int i = t; i < NBLK; i += 256) { s1 += p1[i]; s2 += p2[i]; }
  __shared__ float r1[4], r2[4];
#pragma unroll
  for (int off = 32; off >= 1; off >>= 1) {
    s1 += __shfl_down(s1, off, 64);
    s2 += __shfl_down(s2, off, 64);
  }
  if ((t & 63) == 0) { r1[t >> 6] = s1; r2[t >> 6] = s2; }
  __syncthreads();
  if (t == 0) {
    float S1 = (r1[0] + r1[1]) + (r1[2] + r1[3]);
    float S2 = (r2[0] + r2[1]) + (r2[2] + r2[3]);
    const float invM = 1.0f / (float)MTOT;
    float mu = S1 * invM;
    float var = S2 * invM - mu * mu;
    float rs = 1.0f / sqrtf(var + 1e-5f);
    float a = g[o] * rs;
    ad[o] = a;
    ad[128 + o] = bt[o] - mu * a;
  }
}

// ---------------------------------------------------------------------------
// Final: new_points[(b,s),o] = relu(a * (a>=0 ? max : min) + d)
// ---------------------------------------------------------------------------
__global__ __launch_bounds__(256) void final_kernel(const float* __restrict__ mm,
                                                    const float* __restrict__ ad,
                                                    float* __restrict__ out) {
  int gid = blockIdx.x * 256 + threadIdx.x;   // 8192*128 exactly
  int o = gid & 127;
  float a = ad[o], d = ad[128 + o];
  float y = (a >= 0.0f) ? mm[gid] : mm[8192 * 128 + gid];
  out[gid] = fmaxf(fmaf(a, y, d), 0.0f);
}

extern "C" void kernel_launch(void* const* d_in, const int* in_sizes, int n_in,
                              void* d_out, int out_size, void* d_ws, size_t ws_size,
                              hipStream_t stream) {
  (void)in_sizes; (void)n_in; (void)out_size; (void)ws_size;
  const float* xyz    = (const float*)d_in[0];
  const float* points = (const float*)d_in[1];
  const float* w0  = (const float*)d_in[2];
  const float* b0  = (const float*)d_in[3];
  const float* g0  = (const float*)d_in[4];
  const float* bt0 = (const float*)d_in[5];
  const float* w1  = (const float*)d_in[6];
  const float* b1  = (const float*)d_in[7];
  const float* g1  = (const float*)d_in[8];
  const float* bt1 = (const float*)d_in[9];
  const float* w2  = (const float*)d_in[10];
  const float* b2  = (const float*)d_in[11];
  const float* g2  = (const float*)d_in[12];
  const float* bt2 = (const float*)d_in[13];

  float* out      = (float*)d_out;
  float* new_xyz  = out;                 // 8*1024*3 = 24576 floats
  float* out_pts  = out + 24576;         // 8*1024*128 floats

  float* wsf  = (float*)d_ws;
  int*   gidx = (int*)d_ws;                          // 262144 ints
  float* Y2   = wsf + 262144;                        // 262144*64
  float* Y1   = Y2 + (size_t)MTOT * 68;              // 262144*64
  float* part = Y1 + (size_t)MTOT * 64;              // 2*128*4096
  float* ad1  = part + 2 * 128 * NBLK;               // 256
  float* ad2  = ad1 + 256;
  float* ad3  = ad2 + 256;
  float* mm   = ad3 + 256;                           // 2*8192*128

  fps_kernel<<<NB, 512, 0, stream>>>(xyz, new_xyz);
  ballq_kernel<<<(NB * NPT * 64) / 256, 256, 0, stream>>>(xyz, new_xyz, gidx);

  mlp_gemm_gather<<<NBLK, 256, 0, stream>>>(xyz, points, new_xyz, gidx,
                                            w0, b0, Y1, part);
  bn_finalize<<<64, 256, 0, stream>>>(part, g0, bt0, ad1, 64);

  mlp_gemm<64, true, false><<<NBLK, 256, 0, stream>>>(
      Y1, w1, b1, ad1, Y2, part, nullptr);
  bn_finalize<<<64, 256, 0, stream>>>(part, g1, bt1, ad2, 64);

  mlp_gemm<128, false, true><<<NBLK, 256, 0, stream>>>(
      Y2, w2, b2, ad2, nullptr, part, mm);
  bn_finalize<<<128, 256, 0, stream>>>(part, g2, bt2, ad3, 128);

  final_kernel<<<(8192 * 128) / 256, 256, 0, stream>>>(mm, ad3, out_pts);
}

// Round 8
// 921.748 us; speedup vs baseline: 1.5098x; 1.5098x over previous
//
#include <hip/hip_runtime.h>
#include <cmath>

// Problem constants
#define NB 8
#define NPTS 4096
#define NPT 1024
#define NSAMP 32
#define MTOT (NB*NPT*NSAMP)   // 262144 rows for the MLP
#define NBLK 4096             // MTOT/64 GEMM blocks

typedef float v2f __attribute__((ext_vector_type(2)));

// ---------------------------------------------------------------------------
// Stage 1: farthest point sampling. One block of 8 waves per batch.
// Bitwise-exact f32 replication of the reference (packed mul/add with
// contraction OFF; (dx2+dy2)+dz2 order; argmax first-index tie-break).
// r6 structure (measured 584 us): dist -> pk value tree -> 32-bit DPP wave
// max -> readlane -> 8x ballot -> SALU scan -> uniform u64 key -> lane0
// ds_write -> barrier -> 8-slot sel tree -> sxyz[far] broadcast read.
// NOTE: no dynamically-indexed local arrays anywhere on the loop path —
// r7's px[ih] select lowered the register arrays to scratch (VGPR 88->36,
// +480 cyc/step). Constant indices only.
// ---------------------------------------------------------------------------
__global__ __launch_bounds__(512) void fps_kernel(const float* __restrict__ xyz,
                                                  float* __restrict__ new_xyz) {
#pragma clang fp contract(off)
  const int b = blockIdx.x;
  const int t = threadIdx.x;          // 0..511
  const int wv = t >> 6;              // 0..7
  const int lane = t & 63;
  __shared__ float4 sxyz[NPTS];                  // 64 KiB
  __shared__ float4 sout[NPT];                   // 16 KiB centroid history
  __shared__ unsigned long long skey[2][8];      // parity-buffered wave keys
  const float* X = xyz + (size_t)b * NPTS * 3;
  v2f px[4], py[4], pz[4], dist[4];
#pragma unroll
  for (int i = 0; i < 4; ++i) {
    int p0 = (2 * i) * 512 + t;
    int p1 = (2 * i + 1) * 512 + t;
    float x0 = X[p0 * 3 + 0], y0 = X[p0 * 3 + 1], z0 = X[p0 * 3 + 2];
    float x1 = X[p1 * 3 + 0], y1 = X[p1 * 3 + 1], z1 = X[p1 * 3 + 2];
    px[i] = (v2f){x0, x1}; py[i] = (v2f){y0, y1}; pz[i] = (v2f){z0, z1};
    sxyz[p0] = make_float4(x0, y0, z0, 0.0f);
    sxyz[p1] = make_float4(x1, y1, z1, 0.0f);
    dist[i] = (v2f){1e10f, 1e10f};
  }
  __syncthreads();
  float ccx = X[0], ccy = X[1], ccz = X[2];      // first centroid = point 0
  for (int s = 0; s < NPT; ++s) {
    if (t == 0) sout[s] = make_float4(ccx, ccy, ccz, 0.0f);
    v2f cx = (v2f){ccx, ccx}, cy = (v2f){ccy, ccy}, cz = (v2f){ccz, ccz};
    v2f nd[4];
#pragma unroll
    for (int i = 0; i < 4; ++i) {
      v2f dx = px[i] - cx;
      v2f dy = py[i] - cy;
      v2f dz = pz[i] - cz;
      v2f d = (dx * dx + dy * dy) + dz * dz;     // contract(off): ref order
      v2f m = __builtin_elementwise_min(dist[i], d);
      dist[i] = m;
      nd[i] = m;
    }
    // per-lane max value (no index tracking): depth-2 pk tree + halves merge
    v2f t01 = __builtin_elementwise_max(nd[0], nd[1]);
    v2f t23 = __builtin_elementwise_max(nd[2], nd[3]);
    v2f t03 = __builtin_elementwise_max(t01, t23);
    float lmax = fmaxf(t03.x, t03.y);
    // 32-bit DPP wave max on value bits (all values >= +0 -> unsigned order)
    unsigned km = __float_as_uint(lmax);
    {
      unsigned o;
      o = (unsigned)__builtin_amdgcn_update_dpp(0, (int)km, 0x111, 0xf, 0xf, false);
      km = o > km ? o : km;   // row_shr:1
      o = (unsigned)__builtin_amdgcn_update_dpp(0, (int)km, 0x112, 0xf, 0xf, false);
      km = o > km ? o : km;   // row_shr:2
      o = (unsigned)__builtin_amdgcn_update_dpp(0, (int)km, 0x114, 0xf, 0xf, false);
      km = o > km ? o : km;   // row_shr:4
      o = (unsigned)__builtin_amdgcn_update_dpp(0, (int)km, 0x118, 0xf, 0xf, false);
      km = o > km ? o : km;   // row_shr:8
      o = (unsigned)__builtin_amdgcn_update_dpp(0, (int)km, 0x142, 0xf, 0xf, false);
      km = o > km ? o : km;   // row_bcast:15
      o = (unsigned)__builtin_amdgcn_update_dpp(0, (int)km, 0x143, 0xf, 0xf, false);
      km = o > km ? o : km;   // row_bcast:31
    }
    unsigned wmax = (unsigned)__builtin_amdgcn_readlane((int)km, 63);  // uniform
    // ballots per ordinal: ordinal k = point k*512 + t
    unsigned long long m0 = __ballot(__float_as_uint(nd[0].x) == wmax);
    unsigned long long m1 = __ballot(__float_as_uint(nd[0].y) == wmax);
    unsigned long long m2 = __ballot(__float_as_uint(nd[1].x) == wmax);
    unsigned long long m3 = __ballot(__float_as_uint(nd[1].y) == wmax);
    unsigned long long m4 = __ballot(__float_as_uint(nd[2].x) == wmax);
    unsigned long long m5 = __ballot(__float_as_uint(nd[2].y) == wmax);
    unsigned long long m6 = __ballot(__float_as_uint(nd[3].x) == wmax);
    unsigned long long m7 = __ballot(__float_as_uint(nd[3].y) == wmax);
    // first-nonzero scan, prefer smallest ordinal (all uniform -> SALU)
    unsigned long long mk = m7; int ord = 7;
    if (m6) { mk = m6; ord = 6; }
    if (m5) { mk = m5; ord = 5; }
    if (m4) { mk = m4; ord = 4; }
    if (m3) { mk = m3; ord = 3; }
    if (m2) { mk = m2; ord = 2; }
    if (m1) { mk = m1; ord = 1; }
    if (m0) { mk = m0; ord = 0; }
    int wlane = (int)__builtin_ctzll(mk);        // smallest lane in this wave
    int idx = ord * 512 + wv * 64 + wlane;       // global point index
    // key: higher value wins; equal value -> smaller index wins
    unsigned long long key = ((unsigned long long)wmax << 32)
                           | (unsigned int)(~idx);
    int par = s & 1;
    if (lane == 0) skey[par][wv] = key;          // uniform -> 8B store
    __syncthreads();
    // 8-slot u64 max-sel tree
    const ulonglong2* sk = (const ulonglong2*)skey[par];
    ulonglong2 A = sk[0], B = sk[1], C = sk[2], D = sk[3];
    unsigned long long a = A.x > A.y ? A.x : A.y;
    unsigned long long bq = B.x > B.y ? B.x : B.y;
    unsigned long long c = C.x > C.y ? C.x : C.y;
    unsigned long long dq = D.x > D.y ? D.x : D.y;
    unsigned long long ab = a > bq ? a : bq;
    unsigned long long cd = c > dq ? c : dq;
    unsigned long long kf = ab > cd ? ab : cd;
    int far = (int)(~(unsigned int)kf) & (NPTS - 1);
    float4 cc = sxyz[far];
    ccx = cc.x; ccy = cc.y; ccz = cc.z;
  }
  __syncthreads();
  float* outp = new_xyz + (size_t)b * NPT * 3;
  for (int j = t; j < NPT; j += 512) {
    float4 c = sout[j];
    outp[3 * j + 0] = c.x; outp[3 * j + 1] = c.y; outp[3 * j + 2] = c.z;
  }
}

// ---------------------------------------------------------------------------
// Stage 2: ball query. One wave per (b,s). First 32 indices in ascending order
// with dist <= r^2; pad with first match.
// ---------------------------------------------------------------------------
__global__ __launch_bounds__(256) void ballq_kernel(const float* __restrict__ xyz,
                                                    const float* __restrict__ new_xyz,
                                                    int* __restrict__ gidx) {
  int w = (blockIdx.x * 256 + threadIdx.x) >> 6;   // 8192 waves
  int lane = threadIdx.x & 63;
  int b = w >> 10;
  const float* X = xyz + (size_t)b * NPTS * 3;
  float cx = new_xyz[w * 3 + 0], cy = new_xyz[w * 3 + 1], cz = new_xyz[w * 3 + 2];
  int* out = gidx + (size_t)w * NSAMP;
  int cnt = 0, first = -1;
  for (int c = 0; c < NPTS / 64; ++c) {
    int p = c * 64 + lane;
    float dx = __fsub_rn(X[p * 3 + 0], cx);
    float dy = __fsub_rn(X[p * 3 + 1], cy);
    float dz = __fsub_rn(X[p * 3 + 2], cz);
    float d = __fadd_rn(__fadd_rn(__fmul_rn(dx, dx), __fmul_rn(dy, dy)), __fmul_rn(dz, dz));
    bool inr = !(d > 0.04f);   // f32(0.2**2) == 0.04f
    unsigned long long mask = __ballot(inr);
    if (mask) {
      if (first < 0) first = c * 64 + (int)__builtin_ctzll(mask);
      if (inr) {
        int pos = cnt + (int)__builtin_popcountll(mask & ((1ull << lane) - 1ull));
        if (pos < NSAMP) out[pos] = p;
      }
      cnt += (int)__builtin_popcountll(mask);
      if (cnt >= NSAMP) break;
    }
  }
  if (lane >= cnt && lane < NSAMP) out[lane] = first;
}

// ---------------------------------------------------------------------------
// Stage 4a: layer-1 GEMM with FUSED gather (no X0 materialization).
// Column layout permuted to [pts(64) | dxyz(3) | pad]; weights permuted to
// match while staging. 64x64 tile per block, 256 threads.
// ---------------------------------------------------------------------------
__global__ __launch_bounds__(256) void mlp_gemm_gather(
    const float* __restrict__ xyz, const float* __restrict__ points,
    const float* __restrict__ new_xyz, const int* __restrict__ gidx,
    const float* __restrict__ Wg, const float* __restrict__ bias,
    float* __restrict__ Yg, float* __restrict__ partials) {
  constexpr int O = 64, OJ = 4, KP4 = 17;
  __shared__ __align__(16) float sX[64 * 68];
  __shared__ __align__(16) float sWt[68 * O];
  const int t = threadIdx.x;
  const int m0 = blockIdx.x * 64;

  // stage W with permuted rows: k<64 -> W[o*67+k+3]; 64..66 -> W[o*67+k-64]; 67 -> 0
  for (int i = t; i < O * 68; i += 256) {
    int k = i >> 6, o = i & 63;
    float w;
    if (k < 64) w = Wg[o * 67 + k + 3];
    else if (k < 67) w = Wg[o * 67 + (k - 64)];
    else w = 0.0f;
    sWt[k * O + o] = w;
  }
  // stage X tile directly from gathered points/xyz
  {
    int r = t >> 2, q = t & 3;
    int m = m0 + r;
    int idx = gidx[m];
    int b = m >> 15;
    const float* prow = points + ((size_t)b * NPTS + idx) * 64;
#pragma unroll
    for (int c4 = q; c4 < 16; c4 += 4)
      *(float4*)&sX[r * 68 + 4 * c4] = *(const float4*)(prow + 4 * c4);
    if (q == 0) {
      int g = m >> 5;
      const float* xr = xyz + ((size_t)b * NPTS + idx) * 3;
      sX[r * 68 + 64] = __fsub_rn(xr[0], new_xyz[g * 3 + 0]);
      sX[r * 68 + 65] = __fsub_rn(xr[1], new_xyz[g * 3 + 1]);
      sX[r * 68 + 66] = __fsub_rn(xr[2], new_xyz[g * 3 + 2]);
      sX[r * 68 + 67] = 0.0f;
    }
  }
  __syncthreads();

  const int to = t & 15, tm = t >> 4;
  float acc[4][OJ];
#pragma unroll
  for (int i = 0; i < 4; ++i)
#pragma unroll
    for (int j = 0; j < OJ; ++j) acc[i][j] = 0.0f;

#pragma unroll
  for (int k4 = 0; k4 < KP4; ++k4) {
    float xs[4][4];
#pragma unroll
    for (int i = 0; i < 4; ++i) {
      float4 v = *(const float4*)&sX[(4 * tm + i) * 68 + 4 * k4];
      xs[i][0] = v.x; xs[i][1] = v.y; xs[i][2] = v.z; xs[i][3] = v.w;
    }
#pragma unroll
    for (int kk = 0; kk < 4; ++kk) {
      float4 wq = *(const float4*)&sWt[(4 * k4 + kk) * O + OJ * to];
      float wv[4] = {wq.x, wq.y, wq.z, wq.w};
#pragma unroll
      for (int i = 0; i < 4; ++i) {
        float xv = xs[i][kk];
#pragma unroll
        for (int j = 0; j < OJ; ++j) acc[i][j] = fmaf(xv, wv[j], acc[i][j]);
      }
    }
  }
#pragma unroll
  for (int j = 0; j < OJ; ++j) {
    float bb = bias[OJ * to + j];
#pragma unroll
    for (int i = 0; i < 4; ++i) acc[i][j] += bb;
  }
  float ps[OJ], ss[OJ];
#pragma unroll
  for (int j = 0; j < OJ; ++j) {
    ps[j] = ((acc[0][j] + acc[1][j]) + (acc[2][j] + acc[3][j]));
    ss[j] = ((acc[0][j] * acc[0][j] + acc[1][j] * acc[1][j]) +
             (acc[2][j] * acc[2][j] + acc[3][j] * acc[3][j]));
  }
  __syncthreads();
#pragma unroll
  for (int j = 0; j < OJ; ++j) {
    int o = OJ * to + j;
    sX[tm * O + o] = ps[j];
    sX[16 * O + tm * O + o] = ss[j];
  }
  __syncthreads();
  if (t < O) {
    float s1 = 0.0f, s2 = 0.0f;
#pragma unroll
    for (int r2 = 0; r2 < 16; ++r2) { s1 += sX[r2 * O + t]; s2 += sX[16 * O + r2 * O + t]; }
    partials[(size_t)t * NBLK + blockIdx.x] = s1;
    partials[(size_t)(O + t) * NBLK + blockIdx.x] = s2;
  }
#pragma unroll
  for (int i = 0; i < 4; ++i)
    *(float4*)&Yg[(size_t)(m0 + 4 * tm + i) * O + OJ * to] =
        make_float4(acc[i][0], acc[i][1], acc[i][2], acc[i][3]);
}

// ---------------------------------------------------------------------------
// Stage 4b: MLP layer GEMM (layers 2,3). 64xO tile per block, 256 threads.
// Applies previous layer's BN+ReLU (a,d) while staging input.
// DO_MM: max/min-pool pre-activations over k (32 rows) instead of writing Y.
// ---------------------------------------------------------------------------
template<int O, bool WRITE_Y, bool DO_MM>
__global__ __launch_bounds__(256) void mlp_gemm(const float* __restrict__ Xg,
                                                const float* __restrict__ Wg,
                                                const float* __restrict__ bias,
                                                const float* __restrict__ ad,
                                                float* __restrict__ Yg,
                                                float* __restrict__ partials,
                                                float* __restrict__ mm) {
  constexpr int KDIM = 64, KP4 = 16;
  constexpr int OJ = O / 16;            // 4 or 8
  __shared__ __align__(16) float sX[64 * 68];
  __shared__ __align__(16) float sWt[KDIM * O];
  const int t = threadIdx.x;
  const int m0 = blockIdx.x * 64;

  for (int i = t; i < O * KDIM; i += 256) {
    int k = i / O;
    int o = i - k * O;
    sWt[k * O + o] = Wg[o * KDIM + k];
  }
  {
    int r = t >> 2, q = t & 3;
    const float* src = Xg + (size_t)(m0 + r) * KDIM;
    for (int c4 = q; c4 < KP4; c4 += 4) {
      float4 v = *(const float4*)(src + 4 * c4);
      float4 a = *(const float4*)(ad + 4 * c4);
      float4 d = *(const float4*)(ad + 128 + 4 * c4);
      v.x = fmaxf(fmaf(a.x, v.x, d.x), 0.0f);
      v.y = fmaxf(fmaf(a.y, v.y, d.y), 0.0f);
      v.z = fmaxf(fmaf(a.z, v.z, d.z), 0.0f);
      v.w = fmaxf(fmaf(a.w, v.w, d.w), 0.0f);
      *(float4*)&sX[r * 68 + 4 * c4] = v;
    }
  }
  __syncthreads();

  const int to = t & 15, tm = t >> 4;
  float acc[4][OJ];
#pragma unroll
  for (int i = 0; i < 4; ++i)
#pragma unroll
    for (int j = 0; j < OJ; ++j) acc[i][j] = 0.0f;

#pragma unroll
  for (int k4 = 0; k4 < KP4; ++k4) {
    float xs[4][4];
#pragma unroll
    for (int i = 0; i < 4; ++i) {
      float4 v = *(const float4*)&sX[(4 * tm + i) * 68 + 4 * k4];
      xs[i][0] = v.x; xs[i][1] = v.y; xs[i][2] = v.z; xs[i][3] = v.w;
    }
#pragma unroll
    for (int kk = 0; kk < 4; ++kk) {
      float wv[OJ];
#pragma unroll
      for (int j4 = 0; j4 < OJ / 4; ++j4) {
        float4 wq = *(const float4*)&sWt[(4 * k4 + kk) * O + OJ * to + 4 * j4];
        wv[4 * j4 + 0] = wq.x; wv[4 * j4 + 1] = wq.y;
        wv[4 * j4 + 2] = wq.z; wv[4 * j4 + 3] = wq.w;
      }
#pragma unroll
      for (int i = 0; i < 4; ++i) {
        float xv = xs[i][kk];
#pragma unroll
        for (int j = 0; j < OJ; ++j) acc[i][j] = fmaf(xv, wv[j], acc[i][j]);
      }
    }
  }
#pragma unroll
  for (int j = 0; j < OJ; ++j) {
    float bb = bias[OJ * to + j];
#pragma unroll
    for (int i = 0; i < 4; ++i) acc[i][j] += bb;
  }
  float ps[OJ], ss[OJ];
#pragma unroll
  for (int j = 0; j < OJ; ++j) {
    ps[j] = ((acc[0][j] + acc[1][j]) + (acc[2][j] + acc[3][j]));
    ss[j] = ((acc[0][j] * acc[0][j] + acc[1][j] * acc[1][j]) +
             (acc[2][j] * acc[2][j] + acc[3][j] * acc[3][j]));
  }
  __syncthreads();
#pragma unroll
  for (int j = 0; j < OJ; ++j) {
    int o = OJ * to + j;
    sX[tm * O + o] = ps[j];
    sX[16 * O + tm * O + o] = ss[j];
  }
  __syncthreads();
  if (t < O) {
    float s1 = 0.0f, s2 = 0.0f;
#pragma unroll
    for (int r2 = 0; r2 < 16; ++r2) { s1 += sX[r2 * O + t]; s2 += sX[16 * O + r2 * O + t]; }
    partials[(size_t)t * NBLK + blockIdx.x] = s1;
    partials[(size_t)(O + t) * NBLK + blockIdx.x] = s2;
  }
  if constexpr (WRITE_Y) {
#pragma unroll
    for (int i = 0; i < 4; ++i) {
#pragma unroll
      for (int j4 = 0; j4 < OJ / 4; ++j4) {
        *(float4*)&Yg[(size_t)(m0 + 4 * tm + i) * O + OJ * to + 4 * j4] =
            make_float4(acc[i][4 * j4 + 0], acc[i][4 * j4 + 1],
                        acc[i][4 * j4 + 2], acc[i][4 * j4 + 3]);
      }
    }
  }
  if constexpr (DO_MM) {
    float vmx[OJ], vmn[OJ];
#pragma unroll
    for (int j = 0; j < OJ; ++j) {
      vmx[j] = fmaxf(fmaxf(acc[0][j], acc[1][j]), fmaxf(acc[2][j], acc[3][j]));
      vmn[j] = fminf(fminf(acc[0][j], acc[1][j]), fminf(acc[2][j], acc[3][j]));
    }
    __syncthreads();
#pragma unroll
    for (int j = 0; j < OJ; ++j) {
      int o = OJ * to + j;
      sX[tm * O + o] = vmx[j];
      sX[16 * O + tm * O + o] = vmn[j];
    }
    __syncthreads();
    int g = t >> 7, o = t & 127;
    float mx = sX[(g * 8) * O + o];
    float mn = sX[16 * O + (g * 8) * O + o];
#pragma unroll
    for (int r2 = 1; r2 < 8; ++r2) {
      mx = fmaxf(mx, sX[(g * 8 + r2) * O + o]);
      mn = fminf(mn, sX[16 * O + (g * 8 + r2) * O + o]);
    }
    int row = (m0 >> 5) + g;
    mm[(size_t)row * O + o] = mx;
    mm[(size_t)8192 * O + (size_t)row * O + o] = mn;
  }
}

// ---------------------------------------------------------------------------
// BN finalize: reduce 4096 partials per channel -> (a, d), a=g*rsigma,
// d = bt - mu*a. ad layout: a at [0..O), d at [128..128+O).
// ---------------------------------------------------------------------------
__global__ __launch_bounds__(256) void bn_finalize(const float* __restrict__ partials,
                                                   const float* __restrict__ g,
                                                   const float* __restrict__ bt,
                                                   float* __restrict__ ad, int O) {
  int o = blockIdx.x, t = threadIdx.x;
  const float* p1 = partials + (size_t)o * NBLK;
  const float* p2 = partials + (size_t)(O + o) * NBLK;
  float s1 = 0.0f, s2 = 0.0f;
  for (int i = t; i < NBLK; i += 256) { s1 += p1[i]; s2 += p2[i]; }
  __shared__ float r1[4], r2[4];
#pragma unroll
  for (int off = 32; off >= 1; off >>= 1) {
    s1 += __shfl_down(s1, off, 64);
    s2 += __shfl_down(s2, off, 64);
  }
  if ((t & 63) == 0) { r1[t >> 6] = s1; r2[t >> 6] = s2; }
  __syncthreads();
  if (t == 0) {
    float S1 = (r1[0] + r1[1]) + (r1[2] + r1[3]);
    float S2 = (r2[0] + r2[1]) + (r2[2] + r2[3]);
    const float invM = 1.0f / (float)MTOT;
    float mu = S1 * invM;
    float var = S2 * invM - mu * mu;
    float rs = 1.0f / sqrtf(var + 1e-5f);
    float a = g[o] * rs;
    ad[o] = a;
    ad[128 + o] = bt[o] - mu * a;
  }
}

// ---------------------------------------------------------------------------
// Final: new_points[(b,s),o] = relu(a * (a>=0 ? max : min) + d)
// ---------------------------------------------------------------------------
__global__ __launch_bounds__(256) void final_kernel(const float* __restrict__ mm,
                                                    const float* __restrict__ ad,
                                                    float* __restrict__ out) {
  int gid = blockIdx.x * 256 + threadIdx.x;   // 8192*128 exactly
  int o = gid & 127;
  float a = ad[o], d = ad[128 + o];
  float y = (a >= 0.0f) ? mm[gid] : mm[8192 * 128 + gid];
  out[gid] = fmaxf(fmaf(a, y, d), 0.0f);
}

extern "C" void kernel_launch(void* const* d_in, const int* in_sizes, int n_in,
                              void* d_out, int out_size, void* d_ws, size_t ws_size,
                              hipStream_t stream) {
  (void)in_sizes; (void)n_in; (void)out_size; (void)ws_size;
  const float* xyz    = (const float*)d_in[0];
  const float* points = (const float*)d_in[1];
  const float* w0  = (const float*)d_in[2];
  const float* b0  = (const float*)d_in[3];
  const float* g0  = (const float*)d_in[4];
  const float* bt0 = (const float*)d_in[5];
  const float* w1  = (const float*)d_in[6];
  const float* b1  = (const float*)d_in[7];
  const float* g1  = (const float*)d_in[8];
  const float* bt1 = (const float*)d_in[9];
  const float* w2  = (const float*)d_in[10];
  const float* b2  = (const float*)d_in[11];
  const float* g2  = (const float*)d_in[12];
  const float* bt2 = (const float*)d_in[13];

  float* out      = (float*)d_out;
  float* new_xyz  = out;                 // 8*1024*3 = 24576 floats
  float* out_pts  = out + 24576;         // 8*1024*128 floats

  float* wsf  = (float*)d_ws;
  int*   gidx = (int*)d_ws;                          // 262144 ints
  float* Y2   = wsf + 262144;                        // 262144*64
  float* Y1   = Y2 + (size_t)MTOT * 68;              // 262144*64
  float* part = Y1 + (size_t)MTOT * 64;              // 2*128*4096
  float* ad1  = part + 2 * 128 * NBLK;               // 256
  float* ad2  = ad1 + 256;
  float* ad3  = ad2 + 256;
  float* mm   = ad3 + 256;                           // 2*8192*128

  fps_kernel<<<NB, 512, 0, stream>>>(xyz, new_xyz);
  ballq_kernel<<<(NB * NPT * 64) / 256, 256, 0, stream>>>(xyz, new_xyz, gidx);

  mlp_gemm_gather<<<NBLK, 256, 0, stream>>>(xyz, points, new_xyz, gidx,
                                            w0, b0, Y1, part);
  bn_finalize<<<64, 256, 0, stream>>>(part, g0, bt0, ad1, 64);

  mlp_gemm<64, true, false><<<NBLK, 256, 0, stream>>>(
      Y1, w1, b1, ad1, Y2, part, nullptr);
  bn_finalize<<<64, 256, 0, stream>>>(part, g1, bt1, ad2, 64);

  mlp_gemm<128, false, true><<<NBLK, 256, 0, stream>>>(
      Y2, w2, b2, ad2, nullptr, part, mm);
  bn_finalize<<<128, 256, 0, stream>>>(part, g2, bt2, ad3, 128);

  final_kernel<<<(8192 * 128) / 256, 256, 0, stream>>>(mm, ad3, out_pts);
}

// Round 9
// 856.205 us; speedup vs baseline: 1.6254x; 1.0766x over previous
//
#include <hip/hip_runtime.h>
#include <cmath>

// Problem constants
#define NB 8
#define NPTS 4096
#define NPT 1024
#define NSAMP 32
#define MTOT (NB*NPT*NSAMP)   // 262144 rows for the MLP
#define NBLK 4096             // MTOT/64 GEMM blocks

typedef float v2f __attribute__((ext_vector_type(2)));

// ---------------------------------------------------------------------------
// Stage 0: weight pre-transpose (once per launch, ~2us). Produces [k][o]
// layouts so GEMM blocks stage W with a coalesced float4 memcpy instead of
// a per-block stride-256B transpose (16x L2 over-read, 4096 blocks).
// Wt1: 68x64, rows permuted for the fused-gather layout ([pts64|dxyz3|0]).
// Wt2: 64x64. Wt3: 64x128.
// ---------------------------------------------------------------------------
__global__ __launch_bounds__(256) void prep_weights(
    const float* __restrict__ w0, const float* __restrict__ w1,
    const float* __restrict__ w2, float* __restrict__ Wt1,
    float* __restrict__ Wt2, float* __restrict__ Wt3) {
  int i = blockIdx.x * 256 + threadIdx.x;
  if (i < 68 * 64) {
    int k = i >> 6, o = i & 63;
    float v;
    if (k < 64) v = w0[o * 67 + k + 3];
    else if (k < 67) v = w0[o * 67 + (k - 64)];
    else v = 0.0f;
    Wt1[i] = v;
  }
  int j = i - 68 * 64;
  if (j >= 0 && j < 64 * 64) {
    int k = j >> 6, o = j & 63;
    Wt2[j] = w1[o * 64 + k];
  }
  int l = i - 68 * 64 - 64 * 64;
  if (l >= 0 && l < 64 * 128) {
    int k = l >> 7, o = l & 127;
    Wt3[l] = w2[o * 64 + k];
  }
}

// ---------------------------------------------------------------------------
// Stage 1: farthest point sampling. One block of 8 waves per batch.
// Bitwise-exact f32 replication of the reference (packed mul/add with
// contraction OFF; (dx2+dy2)+dz2 order; argmax first-index tie-break).
// r6 structure (measured 584 us — structural floor of the barrier-per-step
// design): dist -> pk value tree -> 32-bit DPP wave max -> readlane ->
// 8x ballot -> SALU scan -> uniform u64 key -> lane0 ds_write -> barrier ->
// 8-slot sel tree -> sxyz[far] broadcast read.
// NOTE: no dynamically-indexed local arrays on the loop path (r7: scratch
// spill, VGPR 88->36, +480 cyc/step). Constant indices only.
// ---------------------------------------------------------------------------
__global__ __launch_bounds__(512) void fps_kernel(const float* __restrict__ xyz,
                                                  float* __restrict__ new_xyz) {
#pragma clang fp contract(off)
  const int b = blockIdx.x;
  const int t = threadIdx.x;          // 0..511
  const int wv = t >> 6;              // 0..7
  const int lane = t & 63;
  __shared__ float4 sxyz[NPTS];                  // 64 KiB
  __shared__ float4 sout[NPT];                   // 16 KiB centroid history
  __shared__ unsigned long long skey[2][8];      // parity-buffered wave keys
  const float* X = xyz + (size_t)b * NPTS * 3;
  v2f px[4], py[4], pz[4], dist[4];
#pragma unroll
  for (int i = 0; i < 4; ++i) {
    int p0 = (2 * i) * 512 + t;
    int p1 = (2 * i + 1) * 512 + t;
    float x0 = X[p0 * 3 + 0], y0 = X[p0 * 3 + 1], z0 = X[p0 * 3 + 2];
    float x1 = X[p1 * 3 + 0], y1 = X[p1 * 3 + 1], z1 = X[p1 * 3 + 2];
    px[i] = (v2f){x0, x1}; py[i] = (v2f){y0, y1}; pz[i] = (v2f){z0, z1};
    sxyz[p0] = make_float4(x0, y0, z0, 0.0f);
    sxyz[p1] = make_float4(x1, y1, z1, 0.0f);
    dist[i] = (v2f){1e10f, 1e10f};
  }
  __syncthreads();
  float ccx = X[0], ccy = X[1], ccz = X[2];      // first centroid = point 0
  for (int s = 0; s < NPT; ++s) {
    if (t == 0) sout[s] = make_float4(ccx, ccy, ccz, 0.0f);
    v2f cx = (v2f){ccx, ccx}, cy = (v2f){ccy, ccy}, cz = (v2f){ccz, ccz};
    v2f nd[4];
#pragma unroll
    for (int i = 0; i < 4; ++i) {
      v2f dx = px[i] - cx;
      v2f dy = py[i] - cy;
      v2f dz = pz[i] - cz;
      v2f d = (dx * dx + dy * dy) + dz * dz;     // contract(off): ref order
      v2f m = __builtin_elementwise_min(dist[i], d);
      dist[i] = m;
      nd[i] = m;
    }
    // per-lane max value (no index tracking): depth-2 pk tree + halves merge
    v2f t01 = __builtin_elementwise_max(nd[0], nd[1]);
    v2f t23 = __builtin_elementwise_max(nd[2], nd[3]);
    v2f t03 = __builtin_elementwise_max(t01, t23);
    float lmax = fmaxf(t03.x, t03.y);
    // 32-bit DPP wave max on value bits (all values >= +0 -> unsigned order)
    unsigned km = __float_as_uint(lmax);
    {
      unsigned o;
      o = (unsigned)__builtin_amdgcn_update_dpp(0, (int)km, 0x111, 0xf, 0xf, false);
      km = o > km ? o : km;   // row_shr:1
      o = (unsigned)__builtin_amdgcn_update_dpp(0, (int)km, 0x112, 0xf, 0xf, false);
      km = o > km ? o : km;   // row_shr:2
      o = (unsigned)__builtin_amdgcn_update_dpp(0, (int)km, 0x114, 0xf, 0xf, false);
      km = o > km ? o : km;   // row_shr:4
      o = (unsigned)__builtin_amdgcn_update_dpp(0, (int)km, 0x118, 0xf, 0xf, false);
      km = o > km ? o : km;   // row_shr:8
      o = (unsigned)__builtin_amdgcn_update_dpp(0, (int)km, 0x142, 0xf, 0xf, false);
      km = o > km ? o : km;   // row_bcast:15
      o = (unsigned)__builtin_amdgcn_update_dpp(0, (int)km, 0x143, 0xf, 0xf, false);
      km = o > km ? o : km;   // row_bcast:31
    }
    unsigned wmax = (unsigned)__builtin_amdgcn_readlane((int)km, 63);  // uniform
    // ballots per ordinal: ordinal k = point k*512 + t
    unsigned long long m0 = __ballot(__float_as_uint(nd[0].x) == wmax);
    unsigned long long m1 = __ballot(__float_as_uint(nd[0].y) == wmax);
    unsigned long long m2 = __ballot(__float_as_uint(nd[1].x) == wmax);
    unsigned long long m3 = __ballot(__float_as_uint(nd[1].y) == wmax);
    unsigned long long m4 = __ballot(__float_as_uint(nd[2].x) == wmax);
    unsigned long long m5 = __ballot(__float_as_uint(nd[2].y) == wmax);
    unsigned long long m6 = __ballot(__float_as_uint(nd[3].x) == wmax);
    unsigned long long m7 = __ballot(__float_as_uint(nd[3].y) == wmax);
    // first-nonzero scan, prefer smallest ordinal (all uniform -> SALU)
    unsigned long long mk = m7; int ord = 7;
    if (m6) { mk = m6; ord = 6; }
    if (m5) { mk = m5; ord = 5; }
    if (m4) { mk = m4; ord = 4; }
    if (m3) { mk = m3; ord = 3; }
    if (m2) { mk = m2; ord = 2; }
    if (m1) { mk = m1; ord = 1; }
    if (m0) { mk = m0; ord = 0; }
    int wlane = (int)__builtin_ctzll(mk);        // smallest lane in this wave
    int idx = ord * 512 + wv * 64 + wlane;       // global point index
    // key: higher value wins; equal value -> smaller index wins
    unsigned long long key = ((unsigned long long)wmax << 32)
                           | (unsigned int)(~idx);
    int par = s & 1;
    if (lane == 0) skey[par][wv] = key;          // uniform -> 8B store
    __syncthreads();
    // 8-slot u64 max-sel tree
    const ulonglong2* sk = (const ulonglong2*)skey[par];
    ulonglong2 A = sk[0], B = sk[1], C = sk[2], D = sk[3];
    unsigned long long a = A.x > A.y ? A.x : A.y;
    unsigned long long bq = B.x > B.y ? B.x : B.y;
    unsigned long long c = C.x > C.y ? C.x : C.y;
    unsigned long long dq = D.x > D.y ? D.x : D.y;
    unsigned long long ab = a > bq ? a : bq;
    unsigned long long cd = c > dq ? c : dq;
    unsigned long long kf = ab > cd ? ab : cd;
    int far = (int)(~(unsigned int)kf) & (NPTS - 1);
    float4 cc = sxyz[far];
    ccx = cc.x; ccy = cc.y; ccz = cc.z;
  }
  __syncthreads();
  float* outp = new_xyz + (size_t)b * NPT * 3;
  for (int j = t; j < NPT; j += 512) {
    float4 c = sout[j];
    outp[3 * j + 0] = c.x; outp[3 * j + 1] = c.y; outp[3 * j + 2] = c.z;
  }
}

// ---------------------------------------------------------------------------
// Stage 2: ball query. One wave per (b,s). First 32 indices in ascending order
// with dist <= r^2; pad with first match.
// ---------------------------------------------------------------------------
__global__ __launch_bounds__(256) void ballq_kernel(const float* __restrict__ xyz,
                                                    const float* __restrict__ new_xyz,
                                                    int* __restrict__ gidx) {
  int w = (blockIdx.x * 256 + threadIdx.x) >> 6;   // 8192 waves
  int lane = threadIdx.x & 63;
  int b = w >> 10;
  const float* X = xyz + (size_t)b * NPTS * 3;
  float cx = new_xyz[w * 3 + 0], cy = new_xyz[w * 3 + 1], cz = new_xyz[w * 3 + 2];
  int* out = gidx + (size_t)w * NSAMP;
  int cnt = 0, first = -1;
  for (int c = 0; c < NPTS / 64; ++c) {
    int p = c * 64 + lane;
    float dx = __fsub_rn(X[p * 3 + 0], cx);
    float dy = __fsub_rn(X[p * 3 + 1], cy);
    float dz = __fsub_rn(X[p * 3 + 2], cz);
    float d = __fadd_rn(__fadd_rn(__fmul_rn(dx, dx), __fmul_rn(dy, dy)), __fmul_rn(dz, dz));
    bool inr = !(d > 0.04f);   // f32(0.2**2) == 0.04f
    unsigned long long mask = __ballot(inr);
    if (mask) {
      if (first < 0) first = c * 64 + (int)__builtin_ctzll(mask);
      if (inr) {
        int pos = cnt + (int)__builtin_popcountll(mask & ((1ull << lane) - 1ull));
        if (pos < NSAMP) out[pos] = p;
      }
      cnt += (int)__builtin_popcountll(mask);
      if (cnt >= NSAMP) break;
    }
  }
  if (lane >= cnt && lane < NSAMP) out[lane] = first;
}

// ---------------------------------------------------------------------------
// Stage 4a: layer-1 GEMM with FUSED gather (no X0 materialization).
// Column layout [pts(64) | dxyz(3) | pad]; W comes pre-transposed/permuted
// (Wt1, 68x64) so staging is a coalesced float4 memcpy.
// 64x64 tile per block, 256 threads.
// ---------------------------------------------------------------------------
__global__ __launch_bounds__(256) void mlp_gemm_gather(
    const float* __restrict__ xyz, const float* __restrict__ points,
    const float* __restrict__ new_xyz, const int* __restrict__ gidx,
    const float* __restrict__ Wt, const float* __restrict__ bias,
    float* __restrict__ Yg, float* __restrict__ partials) {
  constexpr int O = 64, OJ = 4, KP4 = 17;
  __shared__ __align__(16) float sX[64 * 68];
  __shared__ __align__(16) float sWt[68 * O];
  const int t = threadIdx.x;
  const int m0 = blockIdx.x * 64;

  // stage W: straight coalesced copy (4352 floats)
  for (int i = 4 * t; i < 68 * O; i += 1024)
    *(float4*)&sWt[i] = *(const float4*)(Wt + i);
  // stage X tile directly from gathered points/xyz
  {
    int r = t >> 2, q = t & 3;
    int m = m0 + r;
    int idx = gidx[m];
    int b = m >> 15;
    const float* prow = points + ((size_t)b * NPTS + idx) * 64;
#pragma unroll
    for (int c4 = q; c4 < 16; c4 += 4)
      *(float4*)&sX[r * 68 + 4 * c4] = *(const float4*)(prow + 4 * c4);
    if (q == 0) {
      int g = m >> 5;
      const float* xr = xyz + ((size_t)b * NPTS + idx) * 3;
      sX[r * 68 + 64] = __fsub_rn(xr[0], new_xyz[g * 3 + 0]);
      sX[r * 68 + 65] = __fsub_rn(xr[1], new_xyz[g * 3 + 1]);
      sX[r * 68 + 66] = __fsub_rn(xr[2], new_xyz[g * 3 + 2]);
      sX[r * 68 + 67] = 0.0f;
    }
  }
  __syncthreads();

  const int to = t & 15, tm = t >> 4;
  float acc[4][OJ];
#pragma unroll
  for (int i = 0; i < 4; ++i)
#pragma unroll
    for (int j = 0; j < OJ; ++j) acc[i][j] = 0.0f;

#pragma unroll
  for (int k4 = 0; k4 < KP4; ++k4) {
    float xs[4][4];
#pragma unroll
    for (int i = 0; i < 4; ++i) {
      float4 v = *(const float4*)&sX[(4 * tm + i) * 68 + 4 * k4];
      xs[i][0] = v.x; xs[i][1] = v.y; xs[i][2] = v.z; xs[i][3] = v.w;
    }
#pragma unroll
    for (int kk = 0; kk < 4; ++kk) {
      float4 wq = *(const float4*)&sWt[(4 * k4 + kk) * O + OJ * to];
      float wv[4] = {wq.x, wq.y, wq.z, wq.w};
#pragma unroll
      for (int i = 0; i < 4; ++i) {
        float xv = xs[i][kk];
#pragma unroll
        for (int j = 0; j < OJ; ++j) acc[i][j] = fmaf(xv, wv[j], acc[i][j]);
      }
    }
  }
#pragma unroll
  for (int j = 0; j < OJ; ++j) {
    float bb = bias[OJ * to + j];
#pragma unroll
    for (int i = 0; i < 4; ++i) acc[i][j] += bb;
  }
  float ps[OJ], ss[OJ];
#pragma unroll
  for (int j = 0; j < OJ; ++j) {
    ps[j] = ((acc[0][j] + acc[1][j]) + (acc[2][j] + acc[3][j]));
    ss[j] = ((acc[0][j] * acc[0][j] + acc[1][j] * acc[1][j]) +
             (acc[2][j] * acc[2][j] + acc[3][j] * acc[3][j]));
  }
  __syncthreads();
#pragma unroll
  for (int j = 0; j < OJ; ++j) {
    int o = OJ * to + j;
    sX[tm * O + o] = ps[j];
    sX[16 * O + tm * O + o] = ss[j];
  }
  __syncthreads();
  if (t < O) {
    float s1 = 0.0f, s2 = 0.0f;
#pragma unroll
    for (int r2 = 0; r2 < 16; ++r2) { s1 += sX[r2 * O + t]; s2 += sX[16 * O + r2 * O + t]; }
    partials[(size_t)t * NBLK + blockIdx.x] = s1;
    partials[(size_t)(O + t) * NBLK + blockIdx.x] = s2;
  }
#pragma unroll
  for (int i = 0; i < 4; ++i)
    *(float4*)&Yg[(size_t)(m0 + 4 * tm + i) * O + OJ * to] =
        make_float4(acc[i][0], acc[i][1], acc[i][2], acc[i][3]);
}

// ---------------------------------------------------------------------------
// Stage 4b: MLP layer GEMM (layers 2,3). 64xO tile per block, 256 threads.
// W pre-transposed (coalesced staging). Applies previous layer's BN+ReLU
// (a,d) while staging input. DO_MM: max/min-pool pre-activations over k.
// ---------------------------------------------------------------------------
template<int O, bool WRITE_Y, bool DO_MM>
__global__ __launch_bounds__(256) void mlp_gemm(const float* __restrict__ Xg,
                                                const float* __restrict__ Wt,
                                                const float* __restrict__ bias,
                                                const float* __restrict__ ad,
                                                float* __restrict__ Yg,
                                                float* __restrict__ partials,
                                                float* __restrict__ mm) {
  constexpr int KDIM = 64, KP4 = 16;
  constexpr int OJ = O / 16;            // 4 or 8
  __shared__ __align__(16) float sX[64 * 68];
  __shared__ __align__(16) float sWt[KDIM * O];
  const int t = threadIdx.x;
  const int m0 = blockIdx.x * 64;

  // stage W: straight coalesced copy (KDIM*O floats, 4 or 8 float4/thread)
#pragma unroll
  for (int i = 4 * t; i < KDIM * O; i += 1024)
    *(float4*)&sWt[i] = *(const float4*)(Wt + i);
  {
    int r = t >> 2, q = t & 3;
    const float* src = Xg + (size_t)(m0 + r) * KDIM;
    for (int c4 = q; c4 < KP4; c4 += 4) {
      float4 v = *(const float4*)(src + 4 * c4);
      float4 a = *(const float4*)(ad + 4 * c4);
      float4 d = *(const float4*)(ad + 128 + 4 * c4);
      v.x = fmaxf(fmaf(a.x, v.x, d.x), 0.0f);
      v.y = fmaxf(fmaf(a.y, v.y, d.y), 0.0f);
      v.z = fmaxf(fmaf(a.z, v.z, d.z), 0.0f);
      v.w = fmaxf(fmaf(a.w, v.w, d.w), 0.0f);
      *(float4*)&sX[r * 68 + 4 * c4] = v;
    }
  }
  __syncthreads();

  const int to = t & 15, tm = t >> 4;
  float acc[4][OJ];
#pragma unroll
  for (int i = 0; i < 4; ++i)
#pragma unroll
    for (int j = 0; j < OJ; ++j) acc[i][j] = 0.0f;

#pragma unroll
  for (int k4 = 0; k4 < KP4; ++k4) {
    float xs[4][4];
#pragma unroll
    for (int i = 0; i < 4; ++i) {
      float4 v = *(const float4*)&sX[(4 * tm + i) * 68 + 4 * k4];
      xs[i][0] = v.x; xs[i][1] = v.y; xs[i][2] = v.z; xs[i][3] = v.w;
    }
#pragma unroll
    for (int kk = 0; kk < 4; ++kk) {
      float wv[OJ];
#pragma unroll
      for (int j4 = 0; j4 < OJ / 4; ++j4) {
        float4 wq = *(const float4*)&sWt[(4 * k4 + kk) * O + OJ * to + 4 * j4];
        wv[4 * j4 + 0] = wq.x; wv[4 * j4 + 1] = wq.y;
        wv[4 * j4 + 2] = wq.z; wv[4 * j4 + 3] = wq.w;
      }
#pragma unroll
      for (int i = 0; i < 4; ++i) {
        float xv = xs[i][kk];
#pragma unroll
        for (int j = 0; j < OJ; ++j) acc[i][j] = fmaf(xv, wv[j], acc[i][j]);
      }
    }
  }
#pragma unroll
  for (int j = 0; j < OJ; ++j) {
    float bb = bias[OJ * to + j];
#pragma unroll
    for (int i = 0; i < 4; ++i) acc[i][j] += bb;
  }
  float ps[OJ], ss[OJ];
#pragma unroll
  for (int j = 0; j < OJ; ++j) {
    ps[j] = ((acc[0][j] + acc[1][j]) + (acc[2][j] + acc[3][j]));
    ss[j] = ((acc[0][j] * acc[0][j] + acc[1][j] * acc[1][j]) +
             (acc[2][j] * acc[2][j] + acc[3][j] * acc[3][j]));
  }
  __syncthreads();
#pragma unroll
  for (int j = 0; j < OJ; ++j) {
    int o = OJ * to + j;
    sX[tm * O + o] = ps[j];
    sX[16 * O + tm * O + o] = ss[j];
  }
  __syncthreads();
  if (t < O) {
    float s1 = 0.0f, s2 = 0.0f;
#pragma unroll
    for (int r2 = 0; r2 < 16; ++r2) { s1 += sX[r2 * O + t]; s2 += sX[16 * O + r2 * O + t]; }
    partials[(size_t)t * NBLK + blockIdx.x] = s1;
    partials[(size_t)(O + t) * NBLK + blockIdx.x] = s2;
  }
  if constexpr (WRITE_Y) {
#pragma unroll
    for (int i = 0; i < 4; ++i) {
#pragma unroll
      for (int j4 = 0; j4 < OJ / 4; ++j4) {
        *(float4*)&Yg[(size_t)(m0 + 4 * tm + i) * O + OJ * to + 4 * j4] =
            make_float4(acc[i][4 * j4 + 0], acc[i][4 * j4 + 1],
                        acc[i][4 * j4 + 2], acc[i][4 * j4 + 3]);
      }
    }
  }
  if constexpr (DO_MM) {
    float vmx[OJ], vmn[OJ];
#pragma unroll
    for (int j = 0; j < OJ; ++j) {
      vmx[j] = fmaxf(fmaxf(acc[0][j], acc[1][j]), fmaxf(acc[2][j], acc[3][j]));
      vmn[j] = fminf(fminf(acc[0][j], acc[1][j]), fminf(acc[2][j], acc[3][j]));
    }
    __syncthreads();
#pragma unroll
    for (int j = 0; j < OJ; ++j) {
      int o = OJ * to + j;
      sX[tm * O + o] = vmx[j];
      sX[16 * O + tm * O + o] = vmn[j];
    }
    __syncthreads();
    int g = t >> 7, o = t & 127;
    float mx = sX[(g * 8) * O + o];
    float mn = sX[16 * O + (g * 8) * O + o];
#pragma unroll
    for (int r2 = 1; r2 < 8; ++r2) {
      mx = fmaxf(mx, sX[(g * 8 + r2) * O + o]);
      mn = fminf(mn, sX[16 * O + (g * 8 + r2) * O + o]);
    }
    int row = (m0 >> 5) + g;
    mm[(size_t)row * O + o] = mx;
    mm[(size_t)8192 * O + (size_t)row * O + o] = mn;
  }
}

// ---------------------------------------------------------------------------
// BN finalize: reduce 4096 partials per channel -> (a, d), a=g*rsigma,
// d = bt - mu*a. ad layout: a at [0..O), d at [128..128+O).
// ---------------------------------------------------------------------------
__global__ __launch_bounds__(256) void bn_finalize(const float* __restrict__ partials,
                                                   const float* __restrict__ g,
                                                   const float* __restrict__ bt,
                                                   float* __restrict__ ad, int O) {
  int o = blockIdx.x, t = threadIdx.x;
  const float* p1 = partials + (size_t)o * NBLK;
  const float* p2 = partials + (size_t)(O + o) * NBLK;
  float s1 = 0.0f, s2 = 0.0f;
  for (int i = t; i < NBLK; i += 256) { s1 += p1[i]; s2 += p2[i]; }
  __shared__ float r1[4], r2[4];
#pragma unroll
  for (int off = 32; off >= 1; off >>= 1) {
    s1 += __shfl_down(s1, off, 64);
    s2 += __shfl_down(s2, off, 64);
  }
  if ((t & 63) == 0) { r1[t >> 6] = s1; r2[t >> 6] = s2; }
  __syncthreads();
  if (t == 0) {
    float S1 = (r1[0] + r1[1]) + (r1[2] + r1[3]);
    float S2 = (r2[0] + r2[1]) + (r2[2] + r2[3]);
    const float invM = 1.0f / (float)MTOT;
    float mu = S1 * invM;
    float var = S2 * invM - mu * mu;
    float rs = 1.0f / sqrtf(var + 1e-5f);
    float a = g[o] * rs;
    ad[o] = a;
    ad[128 + o] = bt[o] - mu * a;
  }
}

// ---------------------------------------------------------------------------
// Final: new_points[(b,s),o] = relu(a * (a>=0 ? max : min) + d)
// ---------------------------------------------------------------------------
__global__ __launch_bounds__(256) void final_kernel(const float* __restrict__ mm,
                                                    const float* __restrict__ ad,
                                                    float* __restrict__ out) {
  int gid = blockIdx.x * 256 + threadIdx.x;   // 8192*128 exactly
  int o = gid & 127;
  float a = ad[o], d = ad[128 + o];
  float y = (a >= 0.0f) ? mm[gid] : mm[8192 * 128 + gid];
  out[gid] = fmaxf(fmaf(a, y, d), 0.0f);
}

extern "C" void kernel_launch(void* const* d_in, const int* in_sizes, int n_in,
                              void* d_out, int out_size, void* d_ws, size_t ws_size,
                              hipStream_t stream) {
  (void)in_sizes; (void)n_in; (void)out_size; (void)ws_size;
  const float* xyz    = (const float*)d_in[0];
  const float* points = (const float*)d_in[1];
  const float* w0  = (const float*)d_in[2];
  const float* b0  = (const float*)d_in[3];
  const float* g0  = (const float*)d_in[4];
  const float* bt0 = (const float*)d_in[5];
  const float* w1  = (const float*)d_in[6];
  const float* b1  = (const float*)d_in[7];
  const float* g1  = (const float*)d_in[8];
  const float* bt1 = (const float*)d_in[9];
  const float* w2  = (const float*)d_in[10];
  const float* b2  = (const float*)d_in[11];
  const float* g2  = (const float*)d_in[12];
  const float* bt2 = (const float*)d_in[13];

  float* out      = (float*)d_out;
  float* new_xyz  = out;                 // 8*1024*3 = 24576 floats
  float* out_pts  = out + 24576;         // 8*1024*128 floats

  float* wsf  = (float*)d_ws;
  int*   gidx = (int*)d_ws;                          // 262144 ints
  float* Y2   = wsf + 262144;                        // 262144*64
  float* Y1   = Y2 + (size_t)MTOT * 68;              // 262144*64
  float* part = Y1 + (size_t)MTOT * 64;              // 2*128*4096
  float* ad1  = part + 2 * 128 * NBLK;               // 256
  float* ad2  = ad1 + 256;
  float* ad3  = ad2 + 256;
  float* mm   = ad3 + 256;                           // 2*8192*128
  float* Wt1  = mm + 2 * 8192 * 128;                 // 68*64
  float* Wt2  = Wt1 + 68 * 64;                       // 64*64
  float* Wt3  = Wt2 + 64 * 64;                       // 64*128

  prep_weights<<<65, 256, 0, stream>>>(w0, w1, w2, Wt1, Wt2, Wt3);
  fps_kernel<<<NB, 512, 0, stream>>>(xyz, new_xyz);
  ballq_kernel<<<(NB * NPT * 64) / 256, 256, 0, stream>>>(xyz, new_xyz, gidx);

  mlp_gemm_gather<<<NBLK, 256, 0, stream>>>(xyz, points, new_xyz, gidx,
                                            Wt1, b0, Y1, part);
  bn_finalize<<<64, 256, 0, stream>>>(part, g0, bt0, ad1, 64);

  mlp_gemm<64, true, false><<<NBLK, 256, 0, stream>>>(
      Y1, Wt2, b1, ad1, Y2, part, nullptr);
  bn_finalize<<<64, 256, 0, stream>>>(part, g1, bt1, ad2, 64);

  mlp_gemm<128, false, true><<<NBLK, 256, 0, stream>>>(
      Y2, Wt3, b2, ad2, nullptr, part, mm);
  bn_finalize<<<128, 256, 0, stream>>>(part, g2, bt2, ad3, 128);

  final_kernel<<<(8192 * 128) / 256, 256, 0, stream>>>(mm, ad3, out_pts);
}

// Round 10
// 794.034 us; speedup vs baseline: 1.7527x; 1.0783x over previous
//
#include <hip/hip_runtime.h>
#include <cmath>

// Problem constants
#define NB 8
#define NPTS 4096
#define NPT 1024
#define NSAMP 32
#define MTOT (NB*NPT*NSAMP)   // 262144 rows for the MLP
#define NBLK 4096             // MTOT/64 GEMM blocks

typedef float v2f __attribute__((ext_vector_type(2)));
typedef _Float16 half8 __attribute__((ext_vector_type(8)));
typedef float f32x4 __attribute__((ext_vector_type(4)));

__device__ __forceinline__ unsigned int pk2h(float a, float b) {
  _Float16 ha = (_Float16)a, hb = (_Float16)b;          // v_cvt_f16_f32 (RNE)
  unsigned short ua = __builtin_bit_cast(unsigned short, ha);
  unsigned short ub = __builtin_bit_cast(unsigned short, hb);
  return (unsigned int)ua | ((unsigned int)ub << 16);
}
__device__ __forceinline__ unsigned short f2h(float v) {
  _Float16 h = (_Float16)v;
  return __builtin_bit_cast(unsigned short, h);
}

// ---------------------------------------------------------------------------
// Stage 0: weight prep (once, ~2us): fp32 -> fp16, [o][k] layout (B-operand
// fragments read 8 contiguous halves along k — no transpose needed), k padded
// to the LDS stride. Wt1 bakes in the L1 permutation [pts64|dxyz3|0-pad].
// Wt1: 64x104, Wt2: 64x72, Wt3: 128x72 (ushort).
// ---------------------------------------------------------------------------
__global__ __launch_bounds__(256) void prep_weights(
    const float* __restrict__ w0, const float* __restrict__ w1,
    const float* __restrict__ w2, unsigned short* __restrict__ Wt1,
    unsigned short* __restrict__ Wt2, unsigned short* __restrict__ Wt3) {
  int i = blockIdx.x * 256 + threadIdx.x;
  if (i < 64 * 104) {
    int o = i / 104, k = i - o * 104;
    float v = 0.0f;
    if (k < 64) v = w0[o * 67 + k + 3];
    else if (k < 67) v = w0[o * 67 + (k - 64)];
    Wt1[i] = f2h(v);
  } else if (i < 64 * 104 + 64 * 72) {
    int j = i - 64 * 104;
    int o = j / 72, k = j - o * 72;
    Wt2[j] = (k < 64) ? f2h(w1[o * 64 + k]) : (unsigned short)0;
  } else if (i < 64 * 104 + 64 * 72 + 128 * 72) {
    int l = i - 64 * 104 - 64 * 72;
    int o = l / 72, k = l - o * 72;
    Wt3[l] = (k < 64) ? f2h(w2[o * 64 + k]) : (unsigned short)0;
  }
}

// ---------------------------------------------------------------------------
// Stage 1: farthest point sampling. One block of 8 waves per batch.
// Bitwise-exact f32 replication of the reference. r6 structure (584 us,
// structural floor of the barrier-per-step design). No dynamically-indexed
// local arrays on the loop path (r7: scratch spill). Constant indices only.
// ---------------------------------------------------------------------------
__global__ __launch_bounds__(512) void fps_kernel(const float* __restrict__ xyz,
                                                  float* __restrict__ new_xyz) {
#pragma clang fp contract(off)
  const int b = blockIdx.x;
  const int t = threadIdx.x;          // 0..511
  const int wv = t >> 6;              // 0..7
  const int lane = t & 63;
  __shared__ float4 sxyz[NPTS];                  // 64 KiB
  __shared__ float4 sout[NPT];                   // 16 KiB centroid history
  __shared__ unsigned long long skey[2][8];      // parity-buffered wave keys
  const float* X = xyz + (size_t)b * NPTS * 3;
  v2f px[4], py[4], pz[4], dist[4];
#pragma unroll
  for (int i = 0; i < 4; ++i) {
    int p0 = (2 * i) * 512 + t;
    int p1 = (2 * i + 1) * 512 + t;
    float x0 = X[p0 * 3 + 0], y0 = X[p0 * 3 + 1], z0 = X[p0 * 3 + 2];
    float x1 = X[p1 * 3 + 0], y1 = X[p1 * 3 + 1], z1 = X[p1 * 3 + 2];
    px[i] = (v2f){x0, x1}; py[i] = (v2f){y0, y1}; pz[i] = (v2f){z0, z1};
    sxyz[p0] = make_float4(x0, y0, z0, 0.0f);
    sxyz[p1] = make_float4(x1, y1, z1, 0.0f);
    dist[i] = (v2f){1e10f, 1e10f};
  }
  __syncthreads();
  float ccx = X[0], ccy = X[1], ccz = X[2];      // first centroid = point 0
  for (int s = 0; s < NPT; ++s) {
    if (t == 0) sout[s] = make_float4(ccx, ccy, ccz, 0.0f);
    v2f cx = (v2f){ccx, ccx}, cy = (v2f){ccy, ccy}, cz = (v2f){ccz, ccz};
    v2f nd[4];
#pragma unroll
    for (int i = 0; i < 4; ++i) {
      v2f dx = px[i] - cx;
      v2f dy = py[i] - cy;
      v2f dz = pz[i] - cz;
      v2f d = (dx * dx + dy * dy) + dz * dz;     // contract(off): ref order
      v2f m = __builtin_elementwise_min(dist[i], d);
      dist[i] = m;
      nd[i] = m;
    }
    v2f t01 = __builtin_elementwise_max(nd[0], nd[1]);
    v2f t23 = __builtin_elementwise_max(nd[2], nd[3]);
    v2f t03 = __builtin_elementwise_max(t01, t23);
    float lmax = fmaxf(t03.x, t03.y);
    unsigned km = __float_as_uint(lmax);
    {
      unsigned o;
      o = (unsigned)__builtin_amdgcn_update_dpp(0, (int)km, 0x111, 0xf, 0xf, false);
      km = o > km ? o : km;   // row_shr:1
      o = (unsigned)__builtin_amdgcn_update_dpp(0, (int)km, 0x112, 0xf, 0xf, false);
      km = o > km ? o : km;   // row_shr:2
      o = (unsigned)__builtin_amdgcn_update_dpp(0, (int)km, 0x114, 0xf, 0xf, false);
      km = o > km ? o : km;   // row_shr:4
      o = (unsigned)__builtin_amdgcn_update_dpp(0, (int)km, 0x118, 0xf, 0xf, false);
      km = o > km ? o : km;   // row_shr:8
      o = (unsigned)__builtin_amdgcn_update_dpp(0, (int)km, 0x142, 0xf, 0xf, false);
      km = o > km ? o : km;   // row_bcast:15
      o = (unsigned)__builtin_amdgcn_update_dpp(0, (int)km, 0x143, 0xf, 0xf, false);
      km = o > km ? o : km;   // row_bcast:31
    }
    unsigned wmax = (unsigned)__builtin_amdgcn_readlane((int)km, 63);  // uniform
    unsigned long long m0 = __ballot(__float_as_uint(nd[0].x) == wmax);
    unsigned long long m1 = __ballot(__float_as_uint(nd[0].y) == wmax);
    unsigned long long m2 = __ballot(__float_as_uint(nd[1].x) == wmax);
    unsigned long long m3 = __ballot(__float_as_uint(nd[1].y) == wmax);
    unsigned long long m4 = __ballot(__float_as_uint(nd[2].x) == wmax);
    unsigned long long m5 = __ballot(__float_as_uint(nd[2].y) == wmax);
    unsigned long long m6 = __ballot(__float_as_uint(nd[3].x) == wmax);
    unsigned long long m7 = __ballot(__float_as_uint(nd[3].y) == wmax);
    unsigned long long mk = m7; int ord = 7;
    if (m6) { mk = m6; ord = 6; }
    if (m5) { mk = m5; ord = 5; }
    if (m4) { mk = m4; ord = 4; }
    if (m3) { mk = m3; ord = 3; }
    if (m2) { mk = m2; ord = 2; }
    if (m1) { mk = m1; ord = 1; }
    if (m0) { mk = m0; ord = 0; }
    int wlane = (int)__builtin_ctzll(mk);
    int idx = ord * 512 + wv * 64 + wlane;
    unsigned long long key = ((unsigned long long)wmax << 32)
                           | (unsigned int)(~idx);
    int par = s & 1;
    if (lane == 0) skey[par][wv] = key;
    __syncthreads();
    const ulonglong2* sk = (const ulonglong2*)skey[par];
    ulonglong2 A = sk[0], B = sk[1], C = sk[2], D = sk[3];
    unsigned long long a = A.x > A.y ? A.x : A.y;
    unsigned long long bq = B.x > B.y ? B.x : B.y;
    unsigned long long c = C.x > C.y ? C.x : C.y;
    unsigned long long dq = D.x > D.y ? D.x : D.y;
    unsigned long long ab = a > bq ? a : bq;
    unsigned long long cd = c > dq ? c : dq;
    unsigned long long kf = ab > cd ? ab : cd;
    int far = (int)(~(unsigned int)kf) & (NPTS - 1);
    float4 cc = sxyz[far];
    ccx = cc.x; ccy = cc.y; ccz = cc.z;
  }
  __syncthreads();
  float* outp = new_xyz + (size_t)b * NPT * 3;
  for (int j = t; j < NPT; j += 512) {
    float4 c = sout[j];
    outp[3 * j + 0] = c.x; outp[3 * j + 1] = c.y; outp[3 * j + 2] = c.z;
  }
}

// ---------------------------------------------------------------------------
// Stage 2: ball query. One wave per (b,s). First 32 indices in ascending order
// with dist <= r^2; pad with first match.
// ---------------------------------------------------------------------------
__global__ __launch_bounds__(256) void ballq_kernel(const float* __restrict__ xyz,
                                                    const float* __restrict__ new_xyz,
                                                    int* __restrict__ gidx) {
  int w = (blockIdx.x * 256 + threadIdx.x) >> 6;   // 8192 waves
  int lane = threadIdx.x & 63;
  int b = w >> 10;
  const float* X = xyz + (size_t)b * NPTS * 3;
  float cx = new_xyz[w * 3 + 0], cy = new_xyz[w * 3 + 1], cz = new_xyz[w * 3 + 2];
  int* out = gidx + (size_t)w * NSAMP;
  int cnt = 0, first = -1;
  for (int c = 0; c < NPTS / 64; ++c) {
    int p = c * 64 + lane;
    float dx = __fsub_rn(X[p * 3 + 0], cx);
    float dy = __fsub_rn(X[p * 3 + 1], cy);
    float dz = __fsub_rn(X[p * 3 + 2], cz);
    float d = __fadd_rn(__fadd_rn(__fmul_rn(dx, dx), __fmul_rn(dy, dy)), __fmul_rn(dz, dz));
    bool inr = !(d > 0.04f);   // f32(0.2**2) == 0.04f
    unsigned long long mask = __ballot(inr);
    if (mask) {
      if (first < 0) first = c * 64 + (int)__builtin_ctzll(mask);
      if (inr) {
        int pos = cnt + (int)__builtin_popcountll(mask & ((1ull << lane) - 1ull));
        if (pos < NSAMP) out[pos] = p;
      }
      cnt += (int)__builtin_popcountll(mask);
      if (cnt >= NSAMP) break;
    }
  }
  if (lane >= cnt && lane < NSAMP) out[lane] = first;
}

// ---------------------------------------------------------------------------
// Stage 4: MFMA (fp16 in, fp32 accum) MLP GEMM. 256 thr = 4 waves, 64-row
// tile. Wave w computes rows 16w..16w+15 x O cols via 16x16x32_f16 MFMAs.
// Fragments: A[m=lane&15][k=quad*8+j], B[k=quad*8+j][n=lane&15] — both are
// contiguous 16B LDS reads (A rows staged [m][k], W staged [o][k]).
// C/D: row=quad*4+reg, col=lane&15 (HW-verified mapping).
// Only A/B are fp16-rounded; bias/BN/stats/pool all fp32.
// GATHER: L1 fused gather, K=67 padded to 96. NORM_IN: apply prev BN+ReLU
// while staging. DO_MM: max/min-pool pre-activations over 32-row groups.
// ---------------------------------------------------------------------------
template<int KB, int KS, int O, bool GATHER, bool NORM_IN, bool WRITE_Y, bool DO_MM>
__global__ __launch_bounds__(256) void mfma_gemm(
    const float* __restrict__ Xg, const float* __restrict__ xyz,
    const float* __restrict__ points, const float* __restrict__ new_xyz,
    const int* __restrict__ gidx, const unsigned short* __restrict__ Wt,
    const float* __restrict__ bias, const float* __restrict__ ad,
    float* __restrict__ Yg, float* __restrict__ partials,
    float* __restrict__ mm_out) {
  constexpr int NT = O / 16;
  __shared__ __align__(16) unsigned short sA[64 * KS];
  __shared__ __align__(16) unsigned short sB[O * KS];
  const int t = threadIdx.x;
  const int wv = t >> 6, lane = t & 63;
  const int ml = lane & 15, qd = lane >> 4;
  const int m0 = blockIdx.x * 64;

  // stage B: straight uint4 copy of pre-converted weights
  {
    const uint4* src = (const uint4*)Wt;
    uint4* dst = (uint4*)sB;
    constexpr int NB4 = O * KS / 8;
    for (int i = t; i < NB4; i += 256) dst[i] = src[i];
  }
  // stage A
  if constexpr (GATHER) {
    int r = t >> 2, q = t & 3;          // 4 threads/row, 24 k each (KP=96)
    int m = m0 + r;
    int idx = gidx[m];
    int b = m >> 15;
    const float* prow = points + ((size_t)b * NPTS + idx) * 64;
    unsigned int pk[12];
    if (q < 2) {
#pragma unroll
      for (int j = 0; j < 6; ++j) {
        float4 v = *(const float4*)(prow + q * 24 + 4 * j);
        pk[2 * j] = pk2h(v.x, v.y);
        pk[2 * j + 1] = pk2h(v.z, v.w);
      }
    } else if (q == 2) {                 // k 48..71: pts 48-63, dxyz, zeros
#pragma unroll
      for (int j = 0; j < 4; ++j) {
        float4 v = *(const float4*)(prow + 48 + 4 * j);
        pk[2 * j] = pk2h(v.x, v.y);
        pk[2 * j + 1] = pk2h(v.z, v.w);
      }
      int g = m >> 5;
      const float* xr = xyz + ((size_t)b * NPTS + idx) * 3;
      float dx = __fsub_rn(xr[0], new_xyz[g * 3 + 0]);
      float dy = __fsub_rn(xr[1], new_xyz[g * 3 + 1]);
      float dz = __fsub_rn(xr[2], new_xyz[g * 3 + 2]);
      pk[8] = pk2h(dx, dy);
      pk[9] = pk2h(dz, 0.0f);
      pk[10] = 0; pk[11] = 0;
    } else {                             // k 72..95: zero pad
#pragma unroll
      for (int j = 0; j < 12; ++j) pk[j] = 0;
    }
    uint4* dst = (uint4*)&sA[r * KS + q * 24];
    dst[0] = make_uint4(pk[0], pk[1], pk[2], pk[3]);
    dst[1] = make_uint4(pk[4], pk[5], pk[6], pk[7]);
    dst[2] = make_uint4(pk[8], pk[9], pk[10], pk[11]);
  } else {
    int r = t >> 2, q = t & 3;          // 4 threads/row, 16 k each (K=64)
    const float* src = Xg + (size_t)(m0 + r) * 64 + q * 16;
    unsigned int pk[8];
#pragma unroll
    for (int j = 0; j < 4; ++j) {
      float4 v = *(const float4*)(src + 4 * j);
      if constexpr (NORM_IN) {
        float4 a = *(const float4*)(ad + q * 16 + 4 * j);
        float4 d = *(const float4*)(ad + 128 + q * 16 + 4 * j);
        v.x = fmaxf(fmaf(a.x, v.x, d.x), 0.0f);
        v.y = fmaxf(fmaf(a.y, v.y, d.y), 0.0f);
        v.z = fmaxf(fmaf(a.z, v.z, d.z), 0.0f);
        v.w = fmaxf(fmaf(a.w, v.w, d.w), 0.0f);
      }
      pk[2 * j] = pk2h(v.x, v.y);
      pk[2 * j + 1] = pk2h(v.z, v.w);
    }
    uint4* dst = (uint4*)&sA[r * KS + q * 16];
    dst[0] = make_uint4(pk[0], pk[1], pk[2], pk[3]);
    dst[1] = make_uint4(pk[4], pk[5], pk[6], pk[7]);
  }
  __syncthreads();

  f32x4 acc[NT];
#pragma unroll
  for (int nt = 0; nt < NT; ++nt) acc[nt] = f32x4{0.0f, 0.0f, 0.0f, 0.0f};

#pragma unroll
  for (int kb = 0; kb < KB; ++kb) {
    int kof = kb * 32 + qd * 8;
    uint4 au = *(const uint4*)&sA[(16 * wv + ml) * KS + kof];
    half8 af = __builtin_bit_cast(half8, au);
#pragma unroll
    for (int nt = 0; nt < NT; ++nt) {
      uint4 bu = *(const uint4*)&sB[(nt * 16 + ml) * KS + kof];
      half8 bf = __builtin_bit_cast(half8, bu);
      acc[nt] = __builtin_amdgcn_mfma_f32_16x16x32_f16(af, bf, acc[nt], 0, 0, 0);
    }
  }
  // bias (fp32)
#pragma unroll
  for (int nt = 0; nt < NT; ++nt) {
    float bb = bias[nt * 16 + ml];
    acc[nt][0] += bb; acc[nt][1] += bb; acc[nt][2] += bb; acc[nt][3] += bb;
  }
  // per-lane stats over its 4 rows, then quad-reduce via shuffles
  float s1[NT], s2[NT];
#pragma unroll
  for (int nt = 0; nt < NT; ++nt) {
    f32x4 a4 = acc[nt];
    s1[nt] = (a4[0] + a4[1]) + (a4[2] + a4[3]);
    s2[nt] = (a4[0] * a4[0] + a4[1] * a4[1]) + (a4[2] * a4[2] + a4[3] * a4[3]);
    s1[nt] += __shfl_down(s1[nt], 32, 64);
    s1[nt] += __shfl_down(s1[nt], 16, 64);
    s2[nt] += __shfl_down(s2[nt], 32, 64);
    s2[nt] += __shfl_down(s2[nt], 16, 64);
  }
  if constexpr (WRITE_Y) {
#pragma unroll
    for (int nt = 0; nt < NT; ++nt)
#pragma unroll
      for (int r = 0; r < 4; ++r)
        Yg[(size_t)(m0 + 16 * wv + qd * 4 + r) * O + nt * 16 + ml] = acc[nt][r];
  }
  float mx[NT], mn[NT];
  if constexpr (DO_MM) {
#pragma unroll
    for (int nt = 0; nt < NT; ++nt) {
      f32x4 a4 = acc[nt];
      mx[nt] = fmaxf(fmaxf(a4[0], a4[1]), fmaxf(a4[2], a4[3]));
      mn[nt] = fminf(fminf(a4[0], a4[1]), fminf(a4[2], a4[3]));
      mx[nt] = fmaxf(mx[nt], __shfl_down(mx[nt], 32, 64));
      mx[nt] = fmaxf(mx[nt], __shfl_down(mx[nt], 16, 64));
      mn[nt] = fminf(mn[nt], __shfl_down(mn[nt], 32, 64));
      mn[nt] = fminf(mn[nt], __shfl_down(mn[nt], 16, 64));
    }
  }
  __syncthreads();                       // frag reads done; reuse sA as scratch
  float* scr = (float*)sA;
  if (qd == 0) {
#pragma unroll
    for (int nt = 0; nt < NT; ++nt) {
      scr[wv * O + nt * 16 + ml] = s1[nt];
      scr[4 * O + wv * O + nt * 16 + ml] = s2[nt];
    }
    if constexpr (DO_MM) {
#pragma unroll
      for (int nt = 0; nt < NT; ++nt) {
        scr[8 * O + wv * O + nt * 16 + ml] = mx[nt];
        scr[12 * O + wv * O + nt * 16 + ml] = mn[nt];
      }
    }
  }
  __syncthreads();
  if (t < O) {
    float a = (scr[t] + scr[O + t]) + (scr[2 * O + t] + scr[3 * O + t]);
    float b2 = (scr[4 * O + t] + scr[5 * O + t]) + (scr[6 * O + t] + scr[7 * O + t]);
    partials[(size_t)t * NBLK + blockIdx.x] = a;
    partials[(size_t)(O + t) * NBLK + blockIdx.x] = b2;
  }
  if constexpr (DO_MM) {
    int o = t & 127, g = t >> 7;         // waves {0,1}->group 0, {2,3}->group 1
    float gmx = fmaxf(scr[8 * O + (2 * g) * O + o], scr[8 * O + (2 * g + 1) * O + o]);
    float gmn = fminf(scr[12 * O + (2 * g) * O + o], scr[12 * O + (2 * g + 1) * O + o]);
    int row = (m0 >> 5) + g;
    mm_out[(size_t)row * O + o] = gmx;
    mm_out[(size_t)8192 * O + (size_t)row * O + o] = gmn;
  }
}

// ---------------------------------------------------------------------------
// BN finalize: reduce 4096 partials per channel -> (a, d), a=g*rsigma,
// d = bt - mu*a. ad layout: a at [0..O), d at [128..128+O).
// ---------------------------------------------------------------------------
__global__ __launch_bounds__(256) void bn_finalize(const float* __restrict__ partials,
                                                   const float* __restrict__ g,
                                                   const float* __restrict__ bt,
                                                   float* __restrict__ ad, int O) {
  int o = blockIdx.x, t = threadIdx.x;
  const float* p1 = partials + (size_t)o * NBLK;
  const float* p2 = partials + (size_t)(O + o) * NBLK;
  float s1 = 0.0f, s2 = 0.0f;
  for (int i = t; i < NBLK; i += 256) { s1 += p1[i]; s2 += p2[i]; }
  __shared__ float r1[4], r2[4];
#pragma unroll
  for (int off = 32; off >= 1; off >>= 1) {
    s1 += __shfl_down(s1, off, 64);
    s2 += __shfl_down(s2, off, 64);
  }
  if ((t & 63) == 0) { r1[t >> 6] = s1; r2[t >> 6] = s2; }
  __syncthreads();
  if (t == 0) {
    float S1 = (r1[0] + r1[1]) + (r1[2] + r1[3]);
    float S2 = (r2[0] + r2[1]) + (r2[2] + r2[3]);
    const float invM = 1.0f / (float)MTOT;
    float mu = S1 * invM;
    float var = S2 * invM - mu * mu;
    float rs = 1.0f / sqrtf(var + 1e-5f);
    float a = g[o] * rs;
    ad[o] = a;
    ad[128 + o] = bt[o] - mu * a;
  }
}

// ---------------------------------------------------------------------------
// Final: new_points[(b,s),o] = relu(a * (a>=0 ? max : min) + d)
// ---------------------------------------------------------------------------
__global__ __launch_bounds__(256) void final_kernel(const float* __restrict__ mm,
                                                    const float* __restrict__ ad,
                                                    float* __restrict__ out) {
  int gid = blockIdx.x * 256 + threadIdx.x;   // 8192*128 exactly
  int o = gid & 127;
  float a = ad[o], d = ad[128 + o];
  float y = (a >= 0.0f) ? mm[gid] : mm[8192 * 128 + gid];
  out[gid] = fmaxf(fmaf(a, y, d), 0.0f);
}

extern "C" void kernel_launch(void* const* d_in, const int* in_sizes, int n_in,
                              void* d_out, int out_size, void* d_ws, size_t ws_size,
                              hipStream_t stream) {
  (void)in_sizes; (void)n_in; (void)out_size; (void)ws_size;
  const float* xyz    = (const float*)d_in[0];
  const float* points = (const float*)d_in[1];
  const float* w0  = (const float*)d_in[2];
  const float* b0  = (const float*)d_in[3];
  const float* g0  = (const float*)d_in[4];
  const float* bt0 = (const float*)d_in[5];
  const float* w1  = (const float*)d_in[6];
  const float* b1  = (const float*)d_in[7];
  const float* g1  = (const float*)d_in[8];
  const float* bt1 = (const float*)d_in[9];
  const float* w2  = (const float*)d_in[10];
  const float* b2  = (const float*)d_in[11];
  const float* g2  = (const float*)d_in[12];
  const float* bt2 = (const float*)d_in[13];

  float* out      = (float*)d_out;
  float* new_xyz  = out;                 // 8*1024*3 = 24576 floats
  float* out_pts  = out + 24576;         // 8*1024*128 floats

  float* wsf  = (float*)d_ws;
  int*   gidx = (int*)d_ws;                          // 262144 ints
  float* Y2   = wsf + 262144;                        // 262144*64 (legacy-sized)
  float* Y1   = Y2 + (size_t)MTOT * 68;              // 262144*64
  float* part = Y1 + (size_t)MTOT * 64;              // 2*128*4096
  float* ad1  = part + 2 * 128 * NBLK;               // 256
  float* ad2  = ad1 + 256;
  float* ad3  = ad2 + 256;
  float* mm   = ad3 + 256;                           // 2*8192*128
  unsigned short* Wt1 = (unsigned short*)(mm + 2 * 8192 * 128);  // 64*104
  unsigned short* Wt2 = Wt1 + 64 * 104;                          // 64*72
  unsigned short* Wt3 = Wt2 + 64 * 72;                           // 128*72

  prep_weights<<<80, 256, 0, stream>>>(w0, w1, w2, Wt1, Wt2, Wt3);
  fps_kernel<<<NB, 512, 0, stream>>>(xyz, new_xyz);
  ballq_kernel<<<(NB * NPT * 64) / 256, 256, 0, stream>>>(xyz, new_xyz, gidx);

  mfma_gemm<3, 104, 64, true, false, true, false><<<NBLK, 256, 0, stream>>>(
      nullptr, xyz, points, new_xyz, gidx, Wt1, b0, nullptr, Y1, part, nullptr);
  bn_finalize<<<64, 256, 0, stream>>>(part, g0, bt0, ad1, 64);

  mfma_gemm<2, 72, 64, false, true, true, false><<<NBLK, 256, 0, stream>>>(
      Y1, nullptr, nullptr, nullptr, nullptr, Wt2, b1, ad1, Y2, part, nullptr);
  bn_finalize<<<64, 256, 0, stream>>>(part, g1, bt1, ad2, 64);

  mfma_gemm<2, 72, 128, false, true, false, true><<<NBLK, 256, 0, stream>>>(
      Y2, nullptr, nullptr, nullptr, nullptr, Wt3, b2, ad2, nullptr, part, mm);
  bn_finalize<<<128, 256, 0, stream>>>(part, g2, bt2, ad3, 128);

  final_kernel<<<(8192 * 128) / 256, 256, 0, stream>>>(mm, ad3, out_pts);
}

// Round 11
// 779.678 us; speedup vs baseline: 1.7850x; 1.0184x over previous
//
#include <hip/hip_runtime.h>
#include <cmath>

// Problem constants
#define NB 8
#define NPTS 4096
#define NPT 1024
#define NSAMP 32
#define MTOT (NB*NPT*NSAMP)   // 262144 rows for the MLP
#define NBLK 4096             // MTOT/64 GEMM blocks

typedef float v2f __attribute__((ext_vector_type(2)));
typedef _Float16 half8 __attribute__((ext_vector_type(8)));
typedef float f32x4 __attribute__((ext_vector_type(4)));

__device__ __forceinline__ unsigned int pk2h(float a, float b) {
  _Float16 ha = (_Float16)a, hb = (_Float16)b;          // v_cvt_f16_f32 (RNE)
  unsigned short ua = __builtin_bit_cast(unsigned short, ha);
  unsigned short ub = __builtin_bit_cast(unsigned short, hb);
  return (unsigned int)ua | ((unsigned int)ub << 16);
}
__device__ __forceinline__ unsigned short f2h(float v) {
  _Float16 h = (_Float16)v;
  return __builtin_bit_cast(unsigned short, h);
}

// ---------------------------------------------------------------------------
// Stage 1: farthest point sampling. One block of 8 waves per batch.
// Bitwise-exact f32 replication of the reference. r6 structure (584 us,
// measured structural floor of the barrier-per-step design). No dynamically-
// indexed local arrays on the loop path (r7: scratch spill). Constant
// indices only.
// ---------------------------------------------------------------------------
__global__ __launch_bounds__(512) void fps_kernel(const float* __restrict__ xyz,
                                                  float* __restrict__ new_xyz) {
#pragma clang fp contract(off)
  const int b = blockIdx.x;
  const int t = threadIdx.x;          // 0..511
  const int wv = t >> 6;              // 0..7
  const int lane = t & 63;
  __shared__ float4 sxyz[NPTS];                  // 64 KiB
  __shared__ float4 sout[NPT];                   // 16 KiB centroid history
  __shared__ unsigned long long skey[2][8];      // parity-buffered wave keys
  const float* X = xyz + (size_t)b * NPTS * 3;
  v2f px[4], py[4], pz[4], dist[4];
#pragma unroll
  for (int i = 0; i < 4; ++i) {
    int p0 = (2 * i) * 512 + t;
    int p1 = (2 * i + 1) * 512 + t;
    float x0 = X[p0 * 3 + 0], y0 = X[p0 * 3 + 1], z0 = X[p0 * 3 + 2];
    float x1 = X[p1 * 3 + 0], y1 = X[p1 * 3 + 1], z1 = X[p1 * 3 + 2];
    px[i] = (v2f){x0, x1}; py[i] = (v2f){y0, y1}; pz[i] = (v2f){z0, z1};
    sxyz[p0] = make_float4(x0, y0, z0, 0.0f);
    sxyz[p1] = make_float4(x1, y1, z1, 0.0f);
    dist[i] = (v2f){1e10f, 1e10f};
  }
  __syncthreads();
  float ccx = X[0], ccy = X[1], ccz = X[2];      // first centroid = point 0
  for (int s = 0; s < NPT; ++s) {
    if (t == 0) sout[s] = make_float4(ccx, ccy, ccz, 0.0f);
    v2f cx = (v2f){ccx, ccx}, cy = (v2f){ccy, ccy}, cz = (v2f){ccz, ccz};
    v2f nd[4];
#pragma unroll
    for (int i = 0; i < 4; ++i) {
      v2f dx = px[i] - cx;
      v2f dy = py[i] - cy;
      v2f dz = pz[i] - cz;
      v2f d = (dx * dx + dy * dy) + dz * dz;     // contract(off): ref order
      v2f m = __builtin_elementwise_min(dist[i], d);
      dist[i] = m;
      nd[i] = m;
    }
    v2f t01 = __builtin_elementwise_max(nd[0], nd[1]);
    v2f t23 = __builtin_elementwise_max(nd[2], nd[3]);
    v2f t03 = __builtin_elementwise_max(t01, t23);
    float lmax = fmaxf(t03.x, t03.y);
    unsigned km = __float_as_uint(lmax);
    {
      unsigned o;
      o = (unsigned)__builtin_amdgcn_update_dpp(0, (int)km, 0x111, 0xf, 0xf, false);
      km = o > km ? o : km;   // row_shr:1
      o = (unsigned)__builtin_amdgcn_update_dpp(0, (int)km, 0x112, 0xf, 0xf, false);
      km = o > km ? o : km;   // row_shr:2
      o = (unsigned)__builtin_amdgcn_update_dpp(0, (int)km, 0x114, 0xf, 0xf, false);
      km = o > km ? o : km;   // row_shr:4
      o = (unsigned)__builtin_amdgcn_update_dpp(0, (int)km, 0x118, 0xf, 0xf, false);
      km = o > km ? o : km;   // row_shr:8
      o = (unsigned)__builtin_amdgcn_update_dpp(0, (int)km, 0x142, 0xf, 0xf, false);
      km = o > km ? o : km;   // row_bcast:15
      o = (unsigned)__builtin_amdgcn_update_dpp(0, (int)km, 0x143, 0xf, 0xf, false);
      km = o > km ? o : km;   // row_bcast:31
    }
    unsigned wmax = (unsigned)__builtin_amdgcn_readlane((int)km, 63);  // uniform
    unsigned long long m0 = __ballot(__float_as_uint(nd[0].x) == wmax);
    unsigned long long m1 = __ballot(__float_as_uint(nd[0].y) == wmax);
    unsigned long long m2 = __ballot(__float_as_uint(nd[1].x) == wmax);
    unsigned long long m3 = __ballot(__float_as_uint(nd[1].y) == wmax);
    unsigned long long m4 = __ballot(__float_as_uint(nd[2].x) == wmax);
    unsigned long long m5 = __ballot(__float_as_uint(nd[2].y) == wmax);
    unsigned long long m6 = __ballot(__float_as_uint(nd[3].x) == wmax);
    unsigned long long m7 = __ballot(__float_as_uint(nd[3].y) == wmax);
    unsigned long long mk = m7; int ord = 7;
    if (m6) { mk = m6; ord = 6; }
    if (m5) { mk = m5; ord = 5; }
    if (m4) { mk = m4; ord = 4; }
    if (m3) { mk = m3; ord = 3; }
    if (m2) { mk = m2; ord = 2; }
    if (m1) { mk = m1; ord = 1; }
    if (m0) { mk = m0; ord = 0; }
    int wlane = (int)__builtin_ctzll(mk);
    int idx = ord * 512 + wv * 64 + wlane;
    unsigned long long key = ((unsigned long long)wmax << 32)
                           | (unsigned int)(~idx);
    int par = s & 1;
    if (lane == 0) skey[par][wv] = key;
    __syncthreads();
    const ulonglong2* sk = (const ulonglong2*)skey[par];
    ulonglong2 A = sk[0], B = sk[1], C = sk[2], D = sk[3];
    unsigned long long a = A.x > A.y ? A.x : A.y;
    unsigned long long bq = B.x > B.y ? B.x : B.y;
    unsigned long long c = C.x > C.y ? C.x : C.y;
    unsigned long long dq = D.x > D.y ? D.x : D.y;
    unsigned long long ab = a > bq ? a : bq;
    unsigned long long cd = c > dq ? c : dq;
    unsigned long long kf = ab > cd ? ab : cd;
    int far = (int)(~(unsigned int)kf) & (NPTS - 1);
    float4 cc = sxyz[far];
    ccx = cc.x; ccy = cc.y; ccz = cc.z;
  }
  __syncthreads();
  float* outp = new_xyz + (size_t)b * NPT * 3;
  for (int j = t; j < NPT; j += 512) {
    float4 c = sout[j];
    outp[3 * j + 0] = c.x; outp[3 * j + 1] = c.y; outp[3 * j + 2] = c.z;
  }
}

// ---------------------------------------------------------------------------
// Stage 2: ball query (blocks 0..2047) + weight prep (blocks 2048..2127).
// Ball query: one wave per (b,s), first 32 in-index-order hits, pad w/ first.
// Weight prep: fp32 -> fp16, [o][k] layout with k padded to the LDS stride;
// Wt1 bakes in the L1 permutation [pts64|dxyz3|0-pad].
// ---------------------------------------------------------------------------
__global__ __launch_bounds__(256) void ballq_prep(
    const float* __restrict__ xyz, const float* __restrict__ new_xyz,
    int* __restrict__ gidx,
    const float* __restrict__ w0, const float* __restrict__ w1,
    const float* __restrict__ w2, unsigned short* __restrict__ Wt1,
    unsigned short* __restrict__ Wt2, unsigned short* __restrict__ Wt3) {
  if (blockIdx.x >= 2048) {
    int i = (blockIdx.x - 2048) * 256 + threadIdx.x;   // 0..20479
    if (i < 64 * 104) {
      int o = i / 104, k = i - o * 104;
      float v = 0.0f;
      if (k < 64) v = w0[o * 67 + k + 3];
      else if (k < 67) v = w0[o * 67 + (k - 64)];
      Wt1[i] = f2h(v);
    } else if (i < 64 * 104 + 64 * 72) {
      int j = i - 64 * 104;
      int o = j / 72, k = j - o * 72;
      Wt2[j] = (k < 64) ? f2h(w1[o * 64 + k]) : (unsigned short)0;
    } else {
      int l = i - 64 * 104 - 64 * 72;
      int o = l / 72, k = l - o * 72;
      Wt3[l] = (k < 64) ? f2h(w2[o * 64 + k]) : (unsigned short)0;
    }
    return;
  }
  int w = (blockIdx.x * 256 + threadIdx.x) >> 6;   // 8192 waves
  int lane = threadIdx.x & 63;
  int b = w >> 10;
  const float* X = xyz + (size_t)b * NPTS * 3;
  float cx = new_xyz[w * 3 + 0], cy = new_xyz[w * 3 + 1], cz = new_xyz[w * 3 + 2];
  int* out = gidx + (size_t)w * NSAMP;
  int cnt = 0, first = -1;
  for (int c = 0; c < NPTS / 64; ++c) {
    int p = c * 64 + lane;
    float dx = __fsub_rn(X[p * 3 + 0], cx);
    float dy = __fsub_rn(X[p * 3 + 1], cy);
    float dz = __fsub_rn(X[p * 3 + 2], cz);
    float d = __fadd_rn(__fadd_rn(__fmul_rn(dx, dx), __fmul_rn(dy, dy)), __fmul_rn(dz, dz));
    bool inr = !(d > 0.04f);   // f32(0.2**2) == 0.04f
    unsigned long long mask = __ballot(inr);
    if (mask) {
      if (first < 0) first = c * 64 + (int)__builtin_ctzll(mask);
      if (inr) {
        int pos = cnt + (int)__builtin_popcountll(mask & ((1ull << lane) - 1ull));
        if (pos < NSAMP) out[pos] = p;
      }
      cnt += (int)__builtin_popcountll(mask);
      if (cnt >= NSAMP) break;
    }
  }
  if (lane >= cnt && lane < NSAMP) out[lane] = first;
}

// ---------------------------------------------------------------------------
// Stage 4: MFMA (fp16 in, fp32 accum) MLP GEMM. 256 thr = 4 waves, 64-row
// tile; wave w owns rows 16w..16w+15. 16x16x32_f16 MFMAs; A[m=lane&15]
// [k=quad*8+j], B[k][n=lane&15] — both contiguous 16B LDS reads.
// C/D: row=quad*4+reg, col=lane&15 (HW-verified).
// MODE 0 (GATHER): L1 fused gather from f32 sources, K=67 padded to 96;
//   writes Y fp16. MODE 1 (MID): reads fp16 Y, applies prev BN+ReLU in
//   packed fp16 (adh = fp16 a|d), writes Y fp16. MODE 2 (LAST): like MID
//   but max/min-pools fp32 pre-activations over 32-row groups.
// BN stats always from the fp32 accumulators (pre-store) — fp16 storage
// does not touch the stats path.
// ---------------------------------------------------------------------------
template<int KB, int KS, int O, int MODE>
__global__ __launch_bounds__(256) void mfma_gemm(
    const unsigned short* __restrict__ Xh, const float* __restrict__ xyz,
    const float* __restrict__ points, const float* __restrict__ new_xyz,
    const int* __restrict__ gidx, const unsigned short* __restrict__ Wt,
    const float* __restrict__ bias, const unsigned short* __restrict__ adh,
    unsigned short* __restrict__ Yout, float* __restrict__ partials,
    float* __restrict__ mm_out) {
  constexpr int NT = O / 16;
  constexpr bool WRITE_Y = (MODE != 2);
  constexpr bool DO_MM = (MODE == 2);
  __shared__ __align__(16) unsigned short sA[64 * KS];
  __shared__ __align__(16) unsigned short sB[O * KS];
  const int t = threadIdx.x;
  const int wv = t >> 6, lane = t & 63;
  const int ml = lane & 15, qd = lane >> 4;
  const int m0 = blockIdx.x * 64;

  // stage B: straight uint4 copy of pre-converted weights
  {
    const uint4* src = (const uint4*)Wt;
    uint4* dst = (uint4*)sB;
    constexpr int NB4 = O * KS / 8;
    for (int i = t; i < NB4; i += 256) dst[i] = src[i];
  }
  // stage A
  if constexpr (MODE == 0) {
    int r = t >> 2, q = t & 3;          // 4 threads/row, 24 k each (KP=96)
    int m = m0 + r;
    int idx = gidx[m];
    int b = m >> 15;
    const float* prow = points + ((size_t)b * NPTS + idx) * 64;
    unsigned int pk[12];
    if (q < 2) {
#pragma unroll
      for (int j = 0; j < 6; ++j) {
        float4 v = *(const float4*)(prow + q * 24 + 4 * j);
        pk[2 * j] = pk2h(v.x, v.y);
        pk[2 * j + 1] = pk2h(v.z, v.w);
      }
    } else if (q == 2) {                 // k 48..71: pts 48-63, dxyz, zeros
#pragma unroll
      for (int j = 0; j < 4; ++j) {
        float4 v = *(const float4*)(prow + 48 + 4 * j);
        pk[2 * j] = pk2h(v.x, v.y);
        pk[2 * j + 1] = pk2h(v.z, v.w);
      }
      int g = m >> 5;
      const float* xr = xyz + ((size_t)b * NPTS + idx) * 3;
      float dx = __fsub_rn(xr[0], new_xyz[g * 3 + 0]);
      float dy = __fsub_rn(xr[1], new_xyz[g * 3 + 1]);
      float dz = __fsub_rn(xr[2], new_xyz[g * 3 + 2]);
      pk[8] = pk2h(dx, dy);
      pk[9] = pk2h(dz, 0.0f);
      pk[10] = 0; pk[11] = 0;
    } else {                             // k 72..95: zero pad
#pragma unroll
      for (int j = 0; j < 12; ++j) pk[j] = 0;
    }
    uint4* dst = (uint4*)&sA[r * KS + q * 24];
    dst[0] = make_uint4(pk[0], pk[1], pk[2], pk[3]);
    dst[1] = make_uint4(pk[4], pk[5], pk[6], pk[7]);
    dst[2] = make_uint4(pk[8], pk[9], pk[10], pk[11]);
  } else {
    // fp16 input + packed-fp16 BN+ReLU (a,d from adh; exact relu in fp16)
    int r = t >> 2, q = t & 3;          // 4 threads/row, 16 halves each
    const unsigned short* src = Xh + (size_t)(m0 + r) * 64 + q * 16;
    uint4 y0 = *(const uint4*)(src);
    uint4 y1 = *(const uint4*)(src + 8);
    uint4 a0 = *(const uint4*)(adh + q * 16);
    uint4 a1 = *(const uint4*)(adh + q * 16 + 8);
    uint4 d0 = *(const uint4*)(adh + 128 + q * 16);
    uint4 d1 = *(const uint4*)(adh + 128 + q * 16 + 8);
    half8 yv0 = __builtin_bit_cast(half8, y0);
    half8 yv1 = __builtin_bit_cast(half8, y1);
    half8 av0 = __builtin_bit_cast(half8, a0);
    half8 av1 = __builtin_bit_cast(half8, a1);
    half8 dv0 = __builtin_bit_cast(half8, d0);
    half8 dv1 = __builtin_bit_cast(half8, d1);
    half8 z = (half8)(_Float16)0.0f;
    half8 r0 = __builtin_elementwise_max(av0 * yv0 + dv0, z);
    half8 r1 = __builtin_elementwise_max(av1 * yv1 + dv1, z);
    uint4* dst = (uint4*)&sA[r * KS + q * 16];
    dst[0] = __builtin_bit_cast(uint4, r0);
    dst[1] = __builtin_bit_cast(uint4, r1);
  }
  __syncthreads();

  f32x4 acc[NT];
#pragma unroll
  for (int nt = 0; nt < NT; ++nt) acc[nt] = f32x4{0.0f, 0.0f, 0.0f, 0.0f};

#pragma unroll
  for (int kb = 0; kb < KB; ++kb) {
    int kof = kb * 32 + qd * 8;
    uint4 au = *(const uint4*)&sA[(16 * wv + ml) * KS + kof];
    half8 af = __builtin_bit_cast(half8, au);
#pragma unroll
    for (int nt = 0; nt < NT; ++nt) {
      uint4 bu = *(const uint4*)&sB[(nt * 16 + ml) * KS + kof];
      half8 bf = __builtin_bit_cast(half8, bu);
      acc[nt] = __builtin_amdgcn_mfma_f32_16x16x32_f16(af, bf, acc[nt], 0, 0, 0);
    }
  }
  // bias (fp32)
#pragma unroll
  for (int nt = 0; nt < NT; ++nt) {
    float bb = bias[nt * 16 + ml];
    acc[nt][0] += bb; acc[nt][1] += bb; acc[nt][2] += bb; acc[nt][3] += bb;
  }
  // per-lane stats over its 4 rows, then quad-reduce via shuffles (fp32)
  float s1[NT], s2[NT];
#pragma unroll
  for (int nt = 0; nt < NT; ++nt) {
    f32x4 a4 = acc[nt];
    s1[nt] = (a4[0] + a4[1]) + (a4[2] + a4[3]);
    s2[nt] = (a4[0] * a4[0] + a4[1] * a4[1]) + (a4[2] * a4[2] + a4[3] * a4[3]);
    s1[nt] += __shfl_down(s1[nt], 32, 64);
    s1[nt] += __shfl_down(s1[nt], 16, 64);
    s2[nt] += __shfl_down(s2[nt], 32, 64);
    s2[nt] += __shfl_down(s2[nt], 16, 64);
  }
  if constexpr (WRITE_Y) {
#pragma unroll
    for (int nt = 0; nt < NT; ++nt)
#pragma unroll
      for (int r = 0; r < 4; ++r)
        Yout[(size_t)(m0 + 16 * wv + qd * 4 + r) * 64 + nt * 16 + ml] =
            f2h(acc[nt][r]);
  }
  float mx[NT], mn[NT];
  if constexpr (DO_MM) {
#pragma unroll
    for (int nt = 0; nt < NT; ++nt) {
      f32x4 a4 = acc[nt];
      mx[nt] = fmaxf(fmaxf(a4[0], a4[1]), fmaxf(a4[2], a4[3]));
      mn[nt] = fminf(fminf(a4[0], a4[1]), fminf(a4[2], a4[3]));
      mx[nt] = fmaxf(mx[nt], __shfl_down(mx[nt], 32, 64));
      mx[nt] = fmaxf(mx[nt], __shfl_down(mx[nt], 16, 64));
      mn[nt] = fminf(mn[nt], __shfl_down(mn[nt], 32, 64));
      mn[nt] = fminf(mn[nt], __shfl_down(mn[nt], 16, 64));
    }
  }
  __syncthreads();                       // frag reads done; reuse sA as scratch
  float* scr = (float*)sA;
  if (qd == 0) {
#pragma unroll
    for (int nt = 0; nt < NT; ++nt) {
      scr[wv * O + nt * 16 + ml] = s1[nt];
      scr[4 * O + wv * O + nt * 16 + ml] = s2[nt];
    }
    if constexpr (DO_MM) {
#pragma unroll
      for (int nt = 0; nt < NT; ++nt) {
        scr[8 * O + wv * O + nt * 16 + ml] = mx[nt];
        scr[12 * O + wv * O + nt * 16 + ml] = mn[nt];
      }
    }
  }
  __syncthreads();
  if (t < O) {
    float a = (scr[t] + scr[O + t]) + (scr[2 * O + t] + scr[3 * O + t]);
    float b2 = (scr[4 * O + t] + scr[5 * O + t]) + (scr[6 * O + t] + scr[7 * O + t]);
    partials[(size_t)t * NBLK + blockIdx.x] = a;
    partials[(size_t)(O + t) * NBLK + blockIdx.x] = b2;
  }
  if constexpr (DO_MM) {
    int o = t & 127, g = t >> 7;         // waves {0,1}->group 0, {2,3}->group 1
    float gmx = fmaxf(scr[8 * O + (2 * g) * O + o], scr[8 * O + (2 * g + 1) * O + o]);
    float gmn = fminf(scr[12 * O + (2 * g) * O + o], scr[12 * O + (2 * g + 1) * O + o]);
    int row = (m0 >> 5) + g;
    mm_out[(size_t)row * O + o] = gmx;
    mm_out[(size_t)8192 * O + (size_t)row * O + o] = gmn;
  }
}

// ---------------------------------------------------------------------------
// BN finalize: reduce 4096 partials per channel -> (a, d), a=g*rsigma,
// d = bt - mu*a. Writes f32 ad (a at [0..O), d at [128..128+O)) and the
// packed fp16 copy adh (same layout) consumed by the fp16 staging path.
// ---------------------------------------------------------------------------
__global__ __launch_bounds__(256) void bn_finalize(const float* __restrict__ partials,
                                                   const float* __restrict__ g,
                                                   const float* __restrict__ bt,
                                                   float* __restrict__ ad,
                                                   unsigned short* __restrict__ adh,
                                                   int O) {
  int o = blockIdx.x, t = threadIdx.x;
  const float* p1 = partials + (size_t)o * NBLK;
  const float* p2 = partials + (size_t)(O + o) * NBLK;
  float s1 = 0.0f, s2 = 0.0f;
  for (int i = t; i < NBLK; i += 256) { s1 += p1[i]; s2 += p2[i]; }
  __shared__ float r1[4], r2[4];
#pragma unroll
  for (int off = 32; off >= 1; off >>= 1) {
    s1 += __shfl_down(s1, off, 64);
    s2 += __shfl_down(s2, off, 64);
  }
  if ((t & 63) == 0) { r1[t >> 6] = s1; r2[t >> 6] = s2; }
  __syncthreads();
  if (t == 0) {
    float S1 = (r1[0] + r1[1]) + (r1[2] + r1[3]);
    float S2 = (r2[0] + r2[1]) + (r2[2] + r2[3]);
    const float invM = 1.0f / (float)MTOT;
    float mu = S1 * invM;
    float var = S2 * invM - mu * mu;
    float rs = 1.0f / sqrtf(var + 1e-5f);
    float a = g[o] * rs;
    float dv = bt[o] - mu * a;
    ad[o] = a;
    ad[128 + o] = dv;
    adh[o] = f2h(a);
    adh[128 + o] = f2h(dv);
  }
}

// ---------------------------------------------------------------------------
// Final: new_points[(b,s),o] = relu(a * (a>=0 ? max : min) + d)   (all fp32)
// ---------------------------------------------------------------------------
__global__ __launch_bounds__(256) void final_kernel(const float* __restrict__ mm,
                                                    const float* __restrict__ ad,
                                                    float* __restrict__ out) {
  int gid = blockIdx.x * 256 + threadIdx.x;   // 8192*128 exactly
  int o = gid & 127;
  float a = ad[o], d = ad[128 + o];
  float y = (a >= 0.0f) ? mm[gid] : mm[8192 * 128 + gid];
  out[gid] = fmaxf(fmaf(a, y, d), 0.0f);
}

extern "C" void kernel_launch(void* const* d_in, const int* in_sizes, int n_in,
                              void* d_out, int out_size, void* d_ws, size_t ws_size,
                              hipStream_t stream) {
  (void)in_sizes; (void)n_in; (void)out_size; (void)ws_size;
  const float* xyz    = (const float*)d_in[0];
  const float* points = (const float*)d_in[1];
  const float* w0  = (const float*)d_in[2];
  const float* b0  = (const float*)d_in[3];
  const float* g0  = (const float*)d_in[4];
  const float* bt0 = (const float*)d_in[5];
  const float* w1  = (const float*)d_in[6];
  const float* b1  = (const float*)d_in[7];
  const float* g1  = (const float*)d_in[8];
  const float* bt1 = (const float*)d_in[9];
  const float* w2  = (const float*)d_in[10];
  const float* b2  = (const float*)d_in[11];
  const float* g2  = (const float*)d_in[12];
  const float* bt2 = (const float*)d_in[13];

  float* out      = (float*)d_out;
  float* new_xyz  = out;                 // 8*1024*3 = 24576 floats
  float* out_pts  = out + 24576;         // 8*1024*128 floats

  float* wsf  = (float*)d_ws;
  int*   gidx = (int*)d_ws;                          // 262144 ints
  unsigned short* Y1h = (unsigned short*)(wsf + 262144);      // MTOT*64 fp16
  unsigned short* Y2h = Y1h + (size_t)MTOT * 64;              // MTOT*64 fp16
  float* part = (float*)(Y2h + (size_t)MTOT * 64);            // 2*128*4096
  float* ad1  = part + 2 * 128 * NBLK;               // 256
  float* ad2  = ad1 + 256;
  float* ad3  = ad2 + 256;
  unsigned short* adh1 = (unsigned short*)(ad3 + 256);        // 256
  unsigned short* adh2 = adh1 + 256;
  unsigned short* adh3 = adh2 + 256;
  float* mm   = (float*)(adh3 + 256);                // 2*8192*128
  unsigned short* Wt1 = (unsigned short*)(mm + 2 * 8192 * 128);  // 64*104
  unsigned short* Wt2 = Wt1 + 64 * 104;                          // 64*72
  unsigned short* Wt3 = Wt2 + 64 * 72;                           // 128*72

  fps_kernel<<<NB, 512, 0, stream>>>(xyz, new_xyz);
  ballq_prep<<<2128, 256, 0, stream>>>(xyz, new_xyz, gidx,
                                       w0, w1, w2, Wt1, Wt2, Wt3);

  mfma_gemm<3, 104, 64, 0><<<NBLK, 256, 0, stream>>>(
      nullptr, xyz, points, new_xyz, gidx, Wt1, b0, nullptr, Y1h, part, nullptr);
  bn_finalize<<<64, 256, 0, stream>>>(part, g0, bt0, ad1, adh1, 64);

  mfma_gemm<2, 72, 64, 1><<<NBLK, 256, 0, stream>>>(
      Y1h, nullptr, nullptr, nullptr, nullptr, Wt2, b1, adh1, Y2h, part, nullptr);
  bn_finalize<<<64, 256, 0, stream>>>(part, g1, bt1, ad2, adh2, 64);

  mfma_gemm<2, 72, 128, 2><<<NBLK, 256, 0, stream>>>(
      Y2h, nullptr, nullptr, nullptr, nullptr, Wt3, b2, adh2, nullptr, part, mm);
  bn_finalize<<<128, 256, 0, stream>>>(part, g2, bt2, ad3, adh3, 128);

  final_kernel<<<(8192 * 128) / 256, 256, 0, stream>>>(mm, ad3, out_pts);
}